// Round 2
// baseline (3287.534 us; speedup 1.0000x reference)
//
#include <hip/hip_runtime.h>
#include <math.h>

// ---------------------------------------------------------------------------
// GCN 3-layer forward, bucketed-aggregation design (round 2).
//   1. bin_kernel: slab-bucket edges by dst>>6 (64 nodes/bucket), storing
//      (src,dst) int2. Fixed CAP per bucket avoids any scan.
//   2. bucket_deg_kernel: per-bucket LDS histogram -> dinv = rsqrt(indeg+1).
//   3. per layer: linear (LDS-staged W) then agg64_kernel: one WG per bucket,
//      LDS acc[64][64], sequential edge reads, coalesced H[src] gathers,
//      ds_add_f32 accumulation; epilogue fuses bias (+relu).
//   4. layer 3: 6-wide bucketed aggregate fused with bias + log_softmax.
// ---------------------------------------------------------------------------

#define WS_ALIGN(x) (((x) + 255) & ~(size_t)255)
#define BSZ 64    // nodes per bucket
#define CAP 2560  // slab capacity per bucket (mean E/NB = 2048; ~11 sigma headroom)

// ---------------- bin edges into dst-range slabs ----------------
__global__ void bin_kernel(const int* __restrict__ src, const int* __restrict__ dst,
                           int* __restrict__ cur, int2* __restrict__ slab, int E) {
    int e = blockIdx.x * blockDim.x + threadIdx.x;
    if (e >= E) return;
    int s = src[e], d = dst[e];
    int b = d >> 6;
    int pos = atomicAdd(&cur[b], 1);
    if (pos < CAP) slab[(size_t)b * CAP + pos] = make_int2(s, d);
}

// ---------------- degree (in+1) -> dinv, per bucket ----------------
__global__ __launch_bounds__(256) void bucket_deg_kernel(const int2* __restrict__ slab,
                                                         const int* __restrict__ cnt,
                                                         float* __restrict__ dinv, int n) {
    __shared__ int c[BSZ];
    int b = blockIdx.x, tid = threadIdx.x;
    if (tid < BSZ) c[tid] = 0;
    __syncthreads();
    int m = min(cnt[b], CAP);
    const int2* ep = slab + (size_t)b * CAP;
    for (int j = tid; j < m; j += 256) atomicAdd(&c[ep[j].y & (BSZ - 1)], 1);
    __syncthreads();
    if (tid < BSZ) {
        int node = b * BSZ + tid;
        if (node < n) dinv[node] = rsqrtf((float)(c[tid] + 1));  // +1 self loop
    }
}

// ---------------- linear: Y[n][64] = X[n][K] @ W[K][64] ----------------
template <int K>
__global__ __launch_bounds__(256) void linear_kernel(const float* __restrict__ X,
                                                     const float* __restrict__ W,
                                                     float* __restrict__ Y, int n) {
    __shared__ float Wl[K * 64];
    __shared__ float Xs[4][K];
    const int tid = threadIdx.x;
    for (int i = tid; i < K * 64; i += 256) Wl[i] = W[i];
    const int feat = tid & 63;
    const int sub = tid >> 6;
    for (int base = blockIdx.x * 4; base < n; base += gridDim.x * 4) {
        __syncthreads();
        for (int i = tid; i < 4 * K; i += 256) {
            int r = i / K, c = i % K;
            int node = base + r;
            Xs[r][c] = (node < n) ? X[(size_t)node * K + c] : 0.f;
        }
        __syncthreads();
        int node = base + sub;
        if (node < n) {
            float acc = 0.f;
            #pragma unroll
            for (int k = 0; k < K; ++k) acc = fmaf(Xs[sub][k], Wl[k * 64 + feat], acc);
            Y[(size_t)node * 64 + feat] = acc;
        }
    }
}

// ---------------- linear3: Y[n][6] = X[n][64] @ W[64][6] ----------------
__global__ __launch_bounds__(256) void linear3_kernel(const float* __restrict__ X,
                                                      const float* __restrict__ W,
                                                      float* __restrict__ Y, int n) {
    __shared__ float Wl[64 * 6];
    __shared__ float Xs[32][65];
    const int tid = threadIdx.x;
    for (int i = tid; i < 64 * 6; i += 256) Wl[i] = W[i];
    const int sub = tid >> 3;
    const int feat = tid & 7;
    for (int base = blockIdx.x * 32; base < n; base += gridDim.x * 32) {
        __syncthreads();
        for (int i = tid; i < 32 * 64; i += 256) {
            int r = i >> 6, c = i & 63;
            int node = base + r;
            Xs[r][c] = (node < n) ? X[(size_t)node * 64 + c] : 0.f;
        }
        __syncthreads();
        int node = base + sub;
        if (node < n && feat < 6) {
            float acc = 0.f;
            #pragma unroll
            for (int k = 0; k < 64; ++k) acc = fmaf(Xs[sub][k], Wl[k * 6 + feat], acc);
            Y[(size_t)node * 6 + feat] = acc;
        }
    }
}

// ---------------- bucketed aggregate, 64 feats ----------------
__global__ __launch_bounds__(256) void agg64_kernel(
    const float* __restrict__ H, const float* __restrict__ dinv,
    const int2* __restrict__ slab, const int* __restrict__ cnt,
    const float* __restrict__ bias, float* __restrict__ Out, int n, int do_relu) {
    __shared__ float acc[BSZ * 64];  // 16 KB
    const int b = blockIdx.x, tid = threadIdx.x;
    const int lane = tid & 63, wid = tid >> 6;
    const int base = b * BSZ;
    // init with self-loop contribution
    for (int r = wid; r < BSZ; r += 4) {
        int node = base + r;
        float v = 0.f;
        if (node < n) {
            float di = dinv[node];
            v = H[(size_t)node * 64 + lane] * (di * di);
        }
        acc[r * 64 + lane] = v;
    }
    __syncthreads();
    const int m = min(cnt[b], CAP);
    const int2* ep = slab + (size_t)b * CAP;
    for (int j = wid; j < m; j += 4) {
        int2 e = ep[j];                       // wave-uniform 8B load
        float nrm = dinv[e.x] * dinv[e.y];    // L2-resident 400KB table
        float v = H[(size_t)e.x * 64 + lane] * nrm;  // coalesced 256B gather
        unsafeAtomicAdd(&acc[(e.y - base) * 64 + lane], v);  // ds_add_f32
    }
    __syncthreads();
    for (int r = wid; r < BSZ; r += 4) {
        int node = base + r;
        if (node < n) {
            float v = acc[r * 64 + lane] + bias[lane];
            if (do_relu) v = fmaxf(v, 0.f);
            Out[(size_t)node * 64 + lane] = v;
        }
    }
}

// ---------------- bucketed aggregate, 6 feats + bias + log_softmax ----------------
__global__ __launch_bounds__(256) void agg6_lsm_kernel(
    const float* __restrict__ H, const float* __restrict__ dinv,
    const int2* __restrict__ slab, const int* __restrict__ cnt,
    const float* __restrict__ bias, float* __restrict__ out, int n) {
    __shared__ float acc[BSZ * 8];  // 6 feats padded to 8
    const int b = blockIdx.x, tid = threadIdx.x;
    const int base = b * BSZ;
    for (int i = tid; i < BSZ * 8; i += 256) {
        int r = i >> 3, f = i & 7;
        int node = base + r;
        float v = 0.f;
        if (node < n && f < 6) {
            float di = dinv[node];
            v = H[(size_t)node * 6 + f] * (di * di);
        }
        acc[i] = v;
    }
    __syncthreads();
    const int m = min(cnt[b], CAP);
    const int2* ep = slab + (size_t)b * CAP;
    const int lane = tid & 63, wid = tid >> 6;
    const int slot = lane >> 3, f = lane & 7;
    // each wave handles 8 edges per iteration (8 lanes per edge, 6 active)
    for (int jb = wid * 8; jb < m; jb += 32) {
        int j = jb + slot;
        if (j < m && f < 6) {
            int2 e = ep[j];
            float nrm = dinv[e.x] * dinv[e.y];
            float v = H[(size_t)e.x * 6 + f] * nrm;
            unsafeAtomicAdd(&acc[((e.y - base) << 3) + f], v);
        }
    }
    __syncthreads();
    if (tid < BSZ) {
        int node = base + tid;
        if (node < n) {
            float a[6];
            #pragma unroll
            for (int q = 0; q < 6; ++q) a[q] = acc[(tid << 3) + q] + bias[q];
            float mx = a[0];
            #pragma unroll
            for (int q = 1; q < 6; ++q) mx = fmaxf(mx, a[q]);
            float sum = 0.f;
            #pragma unroll
            for (int q = 0; q < 6; ++q) sum += expf(a[q] - mx);
            float lse = mx + logf(sum);
            #pragma unroll
            for (int q = 0; q < 6; ++q) out[(size_t)node * 6 + q] = a[q] - lse;
        }
    }
}

// ---------------------------------------------------------------------------
extern "C" void kernel_launch(void* const* d_in, const int* in_sizes, int n_in,
                              void* d_out, int out_size, void* d_ws, size_t ws_size,
                              hipStream_t stream) {
    const float* x  = (const float*)d_in[0];
    const int*   ei = (const int*)d_in[1];
    const float* W1 = (const float*)d_in[2];
    const float* b1 = (const float*)d_in[3];
    const float* W2 = (const float*)d_in[4];
    const float* b2 = (const float*)d_in[5];
    const float* W3 = (const float*)d_in[6];
    const float* b3 = (const float*)d_in[7];
    float* out = (float*)d_out;

    const int n = in_sizes[0] / 128;  // 100000
    const int E = in_sizes[1] / 2;    // 3200000
    const int* src = ei;
    const int* dst = ei + E;
    const int NB = (n + BSZ - 1) / BSZ;  // 1563 buckets

    // ---- workspace carve ----
    char* ws = (char*)d_ws;
    auto carve = [&](size_t bytes) { char* p = ws; ws += WS_ALIGN(bytes); return p; };
    int*   cur  = (int*)  carve((size_t)NB * 4);
    float* dinv = (float*)carve((size_t)n * 4);
    int2*  slab = (int2*) carve((size_t)NB * CAP * 8);   // 32 MB
    float* bufA = (float*)carve((size_t)n * 64 * 4);     // 25.6 MB
    float* bufB = (float*)carve((size_t)n * 64 * 4);     // 25.6 MB
    float* bufC = (float*)carve((size_t)n * 6 * 4);      // 2.4 MB
    (void)ws_size; (void)n_in; (void)out_size;

    // ---- build binned edge slabs (ws re-poisoned every call) ----
    hipMemsetAsync(cur, 0, (size_t)NB * 4, stream);
    bin_kernel<<<(E + 255) / 256, 256, 0, stream>>>(src, dst, cur, slab, E);
    bucket_deg_kernel<<<NB, 256, 0, stream>>>(slab, cur, dinv, n);

    // ---- layer 1 ----
    linear_kernel<128><<<2048, 256, 0, stream>>>(x, W1, bufA, n);
    agg64_kernel<<<NB, 256, 0, stream>>>(bufA, dinv, slab, cur, b1, bufB, n, 1);

    // ---- layer 2 ----
    linear_kernel<64><<<2048, 256, 0, stream>>>(bufB, W2, bufA, n);
    agg64_kernel<<<NB, 256, 0, stream>>>(bufA, dinv, slab, cur, b2, bufB, n, 1);

    // ---- layer 3 ----
    linear3_kernel<<<2048, 256, 0, stream>>>(bufB, W3, bufC, n);
    agg6_lsm_kernel<<<NB, 256, 0, stream>>>(bufC, dinv, slab, cur, b3, out, n);
}

// Round 3
// 2750.856 us; speedup vs baseline: 1.1951x; 1.1951x over previous
//
#include <hip/hip_runtime.h>
#include <math.h>

// ---------------------------------------------------------------------------
// GCN 3-layer forward, round 3.
// Math refactor: out[i] = dinv[i] * ( sum_{e:dst=i} Hs[src] + Hs[i] ) + b,
// where Hs = (X@W) * dinv  (dinv folded into linear epilogue).
// Edges packed to 4B: w = (src<<6) | (dst&63), bucketed by dst>>6 (64 nodes).
//   1. bin_kernel: LDS-histogram chunked binning (one global reservation per
//      bucket per WG) -> packed slab, clustered writes.
//   2. bucket_deg_kernel: per-bucket LDS histogram -> dinv = rsqrt(indeg+1).
//   3. linear (LDS W, epilogue *dinv) -> agg64 (512 thr, ILP-8 gathers,
//      ds_add_f32 into LDS acc[64][64], epilogue *dinv + bias + relu).
//   4. layer 3: 6-wide aggregate + bias + log_softmax.
// ---------------------------------------------------------------------------

#define WS_ALIGN(x) (((x) + 255) & ~(size_t)255)
#define BSZ 64        // nodes per bucket
#define CAP 2688      // slab capacity per bucket (mean 2048, 64-multiple)
#define EPT 16        // edges per thread in bin kernel
#define BIN_CHUNK (256 * EPT)  // 4096 edges per WG

// ---------------- binning: LDS-staged chunked scatter ----------------
__global__ __launch_bounds__(256) void bin_kernel(
    const int* __restrict__ src, const int* __restrict__ dst,
    int* __restrict__ cur, int* __restrict__ slab, int E, int NB) {
    __shared__ int counts[1600];  // NB <= 1563
    const int tid = threadIdx.x;
    const int base = blockIdx.x * BIN_CHUNK;
    for (int i = tid; i < NB; i += 256) counts[i] = 0;
    __syncthreads();
    int b[EPT], w[EPT], lpos[EPT];
    #pragma unroll
    for (int k = 0; k < EPT; ++k) {
        int e = base + k * 256 + tid;
        if (e < E) {
            int s = src[e], d = dst[e];
            b[k] = d >> 6;
            w[k] = (s << 6) | (d & 63);
        } else b[k] = -1;
    }
    #pragma unroll
    for (int k = 0; k < EPT; ++k)
        if (b[k] >= 0) lpos[k] = atomicAdd(&counts[b[k]], 1);
    __syncthreads();
    // reserve a contiguous run per touched bucket; replace count with base
    for (int i = tid; i < NB; i += 256) {
        int c = counts[i];
        counts[i] = c ? atomicAdd(&cur[i], c) : 0;
    }
    __syncthreads();
    #pragma unroll
    for (int k = 0; k < EPT; ++k) {
        if (b[k] >= 0) {
            int pos = counts[b[k]] + lpos[k];
            if (pos < CAP) slab[(size_t)b[k] * CAP + pos] = w[k];
        }
    }
}

// ---------------- degree -> dinv, per bucket ----------------
__global__ __launch_bounds__(256) void bucket_deg_kernel(
    const int* __restrict__ slab, const int* __restrict__ cnt,
    float* __restrict__ dinv, int n) {
    __shared__ int c[BSZ];
    int b = blockIdx.x, tid = threadIdx.x;
    if (tid < BSZ) c[tid] = 0;
    __syncthreads();
    int m = min(cnt[b], CAP);
    const int* sp = slab + (size_t)b * CAP;
    for (int j = tid; j < m; j += 256) atomicAdd(&c[sp[j] & 63], 1);
    __syncthreads();
    if (tid < BSZ) {
        int node = b * BSZ + tid;
        if (node < n) dinv[node] = rsqrtf((float)(c[tid] + 1));  // +1 self loop
    }
}

// ---------------- linear: Y[n][64] = (X[n][K] @ W[K][64]) * dinv[n] ----------------
template <int K>
__global__ __launch_bounds__(256) void linear_kernel(const float* __restrict__ X,
                                                     const float* __restrict__ W,
                                                     const float* __restrict__ dinv,
                                                     float* __restrict__ Y, int n) {
    __shared__ float Wl[K * 64];
    __shared__ float Xs[4][K];
    const int tid = threadIdx.x;
    for (int i = tid; i < K * 64; i += 256) Wl[i] = W[i];
    const int feat = tid & 63;
    const int sub = tid >> 6;
    for (int base = blockIdx.x * 4; base < n; base += gridDim.x * 4) {
        __syncthreads();
        for (int i = tid; i < 4 * K; i += 256) {
            int r = i / K, c = i % K;
            int node = base + r;
            Xs[r][c] = (node < n) ? X[(size_t)node * K + c] : 0.f;
        }
        __syncthreads();
        int node = base + sub;
        if (node < n) {
            float acc = 0.f;
            #pragma unroll
            for (int k = 0; k < K; ++k) acc = fmaf(Xs[sub][k], Wl[k * 64 + feat], acc);
            Y[(size_t)node * 64 + feat] = acc * dinv[node];
        }
    }
}

// ---------------- linear3: Y[n][6] = (X[n][64] @ W[64][6]) * dinv[n] ----------------
__global__ __launch_bounds__(256) void linear3_kernel(const float* __restrict__ X,
                                                      const float* __restrict__ W,
                                                      const float* __restrict__ dinv,
                                                      float* __restrict__ Y, int n) {
    __shared__ float Wl[64 * 6];
    __shared__ float Xs[32][65];
    const int tid = threadIdx.x;
    for (int i = tid; i < 64 * 6; i += 256) Wl[i] = W[i];
    const int sub = tid >> 3;
    const int feat = tid & 7;
    for (int base = blockIdx.x * 32; base < n; base += gridDim.x * 32) {
        __syncthreads();
        for (int i = tid; i < 32 * 64; i += 256) {
            int r = i >> 6, c = i & 63;
            int node = base + r;
            Xs[r][c] = (node < n) ? X[(size_t)node * 64 + c] : 0.f;
        }
        __syncthreads();
        int node = base + sub;
        if (node < n && feat < 6) {
            float acc = 0.f;
            #pragma unroll
            for (int k = 0; k < 64; ++k) acc = fmaf(Xs[sub][k], Wl[k * 6 + feat], acc);
            Y[(size_t)node * 6 + feat] = acc * dinv[node];
        }
    }
}

// ---------------- bucketed aggregate, 64 feats, ILP-8 ----------------
__global__ __launch_bounds__(512) void agg64_kernel(
    const float* __restrict__ Hs, const float* __restrict__ dinv,
    const int* __restrict__ slab, const int* __restrict__ cnt,
    const float* __restrict__ bias, float* __restrict__ Out, int n, int do_relu) {
    __shared__ float acc[BSZ * 64];  // 16 KB
    const int b = blockIdx.x, tid = threadIdx.x;
    const int lane = tid & 63, wid = tid >> 6;  // 8 waves
    const int base = b * BSZ;
    // init with self-loop term Hs[i]
    for (int r = wid; r < BSZ; r += 8) {
        int node = base + r;
        acc[r * 64 + lane] = (node < n) ? Hs[(size_t)node * 64 + lane] : 0.f;
    }
    __syncthreads();
    const int m = min(cnt[b], CAP);
    const int* sp = slab + (size_t)b * CAP;
    for (int j0 = wid * 8; j0 < m; j0 += 64) {
        if (j0 + 8 <= m) {
            int4 qa = *(const int4*)(sp + j0);      // 8 packed edges, 2x16B
            int4 qb = *(const int4*)(sp + j0 + 4);
            float v0 = Hs[(size_t)(qa.x >> 6) * 64 + lane];  // 8 gathers in flight
            float v1 = Hs[(size_t)(qa.y >> 6) * 64 + lane];
            float v2 = Hs[(size_t)(qa.z >> 6) * 64 + lane];
            float v3 = Hs[(size_t)(qa.w >> 6) * 64 + lane];
            float v4 = Hs[(size_t)(qb.x >> 6) * 64 + lane];
            float v5 = Hs[(size_t)(qb.y >> 6) * 64 + lane];
            float v6 = Hs[(size_t)(qb.z >> 6) * 64 + lane];
            float v7 = Hs[(size_t)(qb.w >> 6) * 64 + lane];
            unsafeAtomicAdd(&acc[(qa.x & 63) * 64 + lane], v0);  // ds_add_f32
            unsafeAtomicAdd(&acc[(qa.y & 63) * 64 + lane], v1);
            unsafeAtomicAdd(&acc[(qa.z & 63) * 64 + lane], v2);
            unsafeAtomicAdd(&acc[(qa.w & 63) * 64 + lane], v3);
            unsafeAtomicAdd(&acc[(qb.x & 63) * 64 + lane], v4);
            unsafeAtomicAdd(&acc[(qb.y & 63) * 64 + lane], v5);
            unsafeAtomicAdd(&acc[(qb.z & 63) * 64 + lane], v6);
            unsafeAtomicAdd(&acc[(qb.w & 63) * 64 + lane], v7);
        } else {
            for (int j = j0; j < m; ++j) {  // tail block (<8 edges)
                int w = sp[j];
                unsafeAtomicAdd(&acc[(w & 63) * 64 + lane],
                                Hs[(size_t)(w >> 6) * 64 + lane]);
            }
        }
    }
    __syncthreads();
    for (int r = wid; r < BSZ; r += 8) {
        int node = base + r;
        if (node < n) {
            float v = acc[r * 64 + lane] * dinv[node] + bias[lane];
            if (do_relu) v = fmaxf(v, 0.f);
            Out[(size_t)node * 64 + lane] = v;
        }
    }
}

// ---------------- bucketed aggregate, 6 feats + bias + log_softmax ----------------
__global__ __launch_bounds__(512) void agg6_lsm_kernel(
    const float* __restrict__ Hs, const float* __restrict__ dinv,
    const int* __restrict__ slab, const int* __restrict__ cnt,
    const float* __restrict__ bias, float* __restrict__ out, int n) {
    __shared__ float acc[BSZ * 8];  // 6 feats padded to 8
    const int b = blockIdx.x, tid = threadIdx.x;
    const int base = b * BSZ;
    for (int i = tid; i < BSZ * 8; i += 512) {
        int r = i >> 3, f = i & 7;
        int node = base + r;
        acc[i] = (node < n && f < 6) ? Hs[(size_t)node * 6 + f] : 0.f;
    }
    __syncthreads();
    const int m = min(cnt[b], CAP);
    const int* sp = slab + (size_t)b * CAP;
    const int lane = tid & 63, wid = tid >> 6;
    const int slot = lane >> 3, f = lane & 7;
    for (int jb = wid * 8; jb < m; jb += 64) {  // 8 edges per wave-iter
        int j = jb + slot;
        if (j < m && f < 6) {
            int w = sp[j];
            unsafeAtomicAdd(&acc[((w & 63) << 3) + f], Hs[(size_t)(w >> 6) * 6 + f]);
        }
    }
    __syncthreads();
    if (tid < BSZ) {
        int node = base + tid;
        if (node < n) {
            float di = dinv[node];
            float a[6];
            #pragma unroll
            for (int q = 0; q < 6; ++q) a[q] = acc[(tid << 3) + q] * di + bias[q];
            float mx = a[0];
            #pragma unroll
            for (int q = 1; q < 6; ++q) mx = fmaxf(mx, a[q]);
            float sum = 0.f;
            #pragma unroll
            for (int q = 0; q < 6; ++q) sum += expf(a[q] - mx);
            float lse = mx + logf(sum);
            #pragma unroll
            for (int q = 0; q < 6; ++q) out[(size_t)node * 6 + q] = a[q] - lse;
        }
    }
}

// ---------------------------------------------------------------------------
extern "C" void kernel_launch(void* const* d_in, const int* in_sizes, int n_in,
                              void* d_out, int out_size, void* d_ws, size_t ws_size,
                              hipStream_t stream) {
    const float* x  = (const float*)d_in[0];
    const int*   ei = (const int*)d_in[1];
    const float* W1 = (const float*)d_in[2];
    const float* b1 = (const float*)d_in[3];
    const float* W2 = (const float*)d_in[4];
    const float* b2 = (const float*)d_in[5];
    const float* W3 = (const float*)d_in[6];
    const float* b3 = (const float*)d_in[7];
    float* out = (float*)d_out;

    const int n = in_sizes[0] / 128;  // 100000
    const int E = in_sizes[1] / 2;    // 3200000
    const int* src = ei;
    const int* dst = ei + E;
    const int NB = (n + BSZ - 1) / BSZ;  // 1563

    // ---- workspace carve ----
    char* ws = (char*)d_ws;
    auto carve = [&](size_t bytes) { char* p = ws; ws += WS_ALIGN(bytes); return p; };
    int*   cur  = (int*)  carve((size_t)NB * 4);
    float* dinv = (float*)carve((size_t)n * 4);
    int*   slab = (int*)  carve((size_t)NB * CAP * 4);   // 16.8 MB
    float* bufA = (float*)carve((size_t)n * 64 * 4);     // 25.6 MB
    float* bufB = (float*)carve((size_t)n * 64 * 4);     // 25.6 MB
    float* bufC = (float*)carve((size_t)n * 6 * 4);      // 2.4 MB
    (void)ws_size; (void)n_in; (void)out_size;

    // ---- build ----
    hipMemsetAsync(cur, 0, (size_t)NB * 4, stream);
    bin_kernel<<<(E + BIN_CHUNK - 1) / BIN_CHUNK, 256, 0, stream>>>(src, dst, cur, slab, E, NB);
    bucket_deg_kernel<<<NB, 256, 0, stream>>>(slab, cur, dinv, n);

    // ---- layer 1 ----
    linear_kernel<128><<<2048, 256, 0, stream>>>(x, W1, dinv, bufA, n);
    agg64_kernel<<<NB, 512, 0, stream>>>(bufA, dinv, slab, cur, b1, bufB, n, 1);

    // ---- layer 2 ----
    linear_kernel<64><<<2048, 256, 0, stream>>>(bufB, W2, dinv, bufA, n);
    agg64_kernel<<<NB, 512, 0, stream>>>(bufA, dinv, slab, cur, b2, bufB, n, 1);

    // ---- layer 3 ----
    linear3_kernel<<<2048, 256, 0, stream>>>(bufB, W3, dinv, bufC, n);
    agg6_lsm_kernel<<<NB, 512, 0, stream>>>(bufC, dinv, slab, cur, b3, out, n);
}

// Round 4
// 590.709 us; speedup vs baseline: 5.5654x; 4.6569x over previous
//
#include <hip/hip_runtime.h>
#include <math.h>

// ---------------------------------------------------------------------------
// GCN 3-layer forward, round 4.
// out[i] = dinv[i] * ( sum_{e:dst=i} Hs[src] + Hs[i] ) + b,  Hs = (X@W)*dinv.
// Build: bin to 64-node bucket slabs (clustered writes), then per-bucket LDS
// counting sort -> exact per-node CSR (rowbeg/rowend/srcSorted) + dinv.
// Aggregate: wave-per-node (100K waves), register accumulate, unroll-8.
// Layer 3: wave-per-node, 8 edges x 8 feats lanes, fused bias+log_softmax.
// ---------------------------------------------------------------------------

#define WS_ALIGN(x) (((x) + 255) & ~(size_t)255)
#define BSZ 64        // nodes per bucket
#define CAP 2688      // slab capacity per bucket (mean 2048; +14 sigma)
#define EPT 16        // edges per thread in bin kernel
#define BIN_CHUNK (256 * EPT)

// ---------------- binning: LDS-staged chunked scatter ----------------
__global__ __launch_bounds__(256) void bin_kernel(
    const int* __restrict__ src, const int* __restrict__ dst,
    int* __restrict__ cur, int* __restrict__ slab, int E, int NB) {
    __shared__ int counts[1600];  // NB <= 1563
    const int tid = threadIdx.x;
    const int base = blockIdx.x * BIN_CHUNK;
    for (int i = tid; i < NB; i += 256) counts[i] = 0;
    __syncthreads();
    int b[EPT], w[EPT], lpos[EPT];
    #pragma unroll
    for (int k = 0; k < EPT; ++k) {
        int e = base + k * 256 + tid;
        if (e < E) {
            int s = src[e], d = dst[e];
            b[k] = d >> 6;
            w[k] = (s << 6) | (d & 63);
        } else b[k] = -1;
    }
    #pragma unroll
    for (int k = 0; k < EPT; ++k)
        if (b[k] >= 0) lpos[k] = atomicAdd(&counts[b[k]], 1);
    __syncthreads();
    for (int i = tid; i < NB; i += 256) {
        int c = counts[i];
        counts[i] = c ? atomicAdd(&cur[i], c) : 0;
    }
    __syncthreads();
    #pragma unroll
    for (int k = 0; k < EPT; ++k) {
        if (b[k] >= 0) {
            int pos = counts[b[k]] + lpos[k];
            if (pos < CAP) slab[(size_t)b[k] * CAP + pos] = w[k];
        }
    }
}

// ---------------- per-bucket counting sort -> per-node CSR + dinv ----------------
__global__ __launch_bounds__(256) void bucket_sort_kernel(
    const int* __restrict__ slab, const int* __restrict__ cur,
    int* __restrict__ srcS, int* __restrict__ rowbeg, int* __restrict__ rowend,
    float* __restrict__ dinv, int n) {
    __shared__ int cnt[BSZ], ofs[BSZ];
    const int b = blockIdx.x, tid = threadIdx.x;
    const int m = min(cur[b], CAP);
    const int* sp = slab + (size_t)b * CAP;
    if (tid < BSZ) cnt[tid] = 0;
    __syncthreads();
    for (int j = tid; j < m; j += 256) atomicAdd(&cnt[sp[j] & 63], 1);
    __syncthreads();
    if (tid == 0) {
        int run = 0;
        for (int r = 0; r < BSZ; ++r) { ofs[r] = run; run += cnt[r]; }
    }
    __syncthreads();
    if (tid < BSZ) {
        int node = b * BSZ + tid;
        if (node < n) {
            rowbeg[node] = b * CAP + ofs[tid];
            rowend[node] = b * CAP + ofs[tid] + cnt[tid];
            dinv[node] = rsqrtf((float)(cnt[tid] + 1));  // +1 self loop
        }
    }
    __syncthreads();
    if (tid < BSZ) cnt[tid] = ofs[tid];  // reuse as write cursors
    __syncthreads();
    for (int j = tid; j < m; j += 256) {
        int w = sp[j];
        int p = atomicAdd(&cnt[w & 63], 1);
        srcS[(size_t)b * CAP + p] = w >> 6;  // writes land in an 8KB window
    }
}

// ---------------- linear: Y[n][64] = (X[n][K] @ W[K][64]) * dinv[n] ----------------
template <int K>
__global__ __launch_bounds__(256) void linear_kernel(const float* __restrict__ X,
                                                     const float* __restrict__ W,
                                                     const float* __restrict__ dinv,
                                                     float* __restrict__ Y, int n) {
    __shared__ float Wl[K * 64];
    __shared__ float Xs[4][K];
    const int tid = threadIdx.x;
    for (int i = tid; i < K * 64; i += 256) Wl[i] = W[i];
    const int feat = tid & 63;
    const int sub = tid >> 6;
    for (int base = blockIdx.x * 4; base < n; base += gridDim.x * 4) {
        __syncthreads();
        for (int i = tid; i < 4 * K; i += 256) {
            int r = i / K, c = i % K;
            int node = base + r;
            Xs[r][c] = (node < n) ? X[(size_t)node * K + c] : 0.f;
        }
        __syncthreads();
        int node = base + sub;
        if (node < n) {
            float acc = 0.f;
            #pragma unroll
            for (int k = 0; k < K; ++k) acc = fmaf(Xs[sub][k], Wl[k * 64 + feat], acc);
            Y[(size_t)node * 64 + feat] = acc * dinv[node];
        }
    }
}

// ---------------- linear3: Y[n][8] = pad8( (X[n][64] @ W[64][6]) * dinv[n] ) ----------------
__global__ __launch_bounds__(256) void linear3_kernel(const float* __restrict__ X,
                                                      const float* __restrict__ W,
                                                      const float* __restrict__ dinv,
                                                      float* __restrict__ Y, int n) {
    __shared__ float Wl[64 * 6];
    __shared__ float Xs[32][65];
    const int tid = threadIdx.x;
    for (int i = tid; i < 64 * 6; i += 256) Wl[i] = W[i];
    const int sub = tid >> 3;   // 32 nodes per block
    const int feat = tid & 7;   // 8 slots, 6 active
    for (int base = blockIdx.x * 32; base < n; base += gridDim.x * 32) {
        __syncthreads();
        for (int i = tid; i < 32 * 64; i += 256) {
            int r = i >> 6, c = i & 63;
            int node = base + r;
            Xs[r][c] = (node < n) ? X[(size_t)node * 64 + c] : 0.f;
        }
        __syncthreads();
        int node = base + sub;
        if (node < n) {
            float r = 0.f;
            if (feat < 6) {
                float acc = 0.f;
                #pragma unroll
                for (int k = 0; k < 64; ++k) acc = fmaf(Xs[sub][k], Wl[k * 6 + feat], acc);
                r = acc * dinv[node];
            }
            Y[(size_t)node * 8 + feat] = r;  // pad feats 6,7 with 0
        }
    }
}

// ---------------- aggregate 64 feats: wave per node, unroll 8 ----------------
__global__ __launch_bounds__(256) void agg64_kernel(
    const float* __restrict__ Hs, const float* __restrict__ dinv,
    const int* __restrict__ srcS, const int* __restrict__ rowbeg,
    const int* __restrict__ rowend, const float* __restrict__ bias,
    float* __restrict__ Out, int n, int do_relu) {
    const int wave = (blockIdx.x * blockDim.x + threadIdx.x) >> 6;
    const int lane = threadIdx.x & 63;
    if (wave >= n) return;
    const int beg = rowbeg[wave], end = rowend[wave];
    float a0 = Hs[(size_t)wave * 64 + lane];  // self-loop term
    float a1 = 0.f, a2 = 0.f, a3 = 0.f;
    int j = beg;
    for (; j + 8 <= end; j += 8) {
        int s0 = srcS[j],     s1 = srcS[j + 1], s2 = srcS[j + 2], s3 = srcS[j + 3];
        int s4 = srcS[j + 4], s5 = srcS[j + 5], s6 = srcS[j + 6], s7 = srcS[j + 7];
        a0 += Hs[(size_t)s0 * 64 + lane];
        a1 += Hs[(size_t)s1 * 64 + lane];
        a2 += Hs[(size_t)s2 * 64 + lane];
        a3 += Hs[(size_t)s3 * 64 + lane];
        a0 += Hs[(size_t)s4 * 64 + lane];
        a1 += Hs[(size_t)s5 * 64 + lane];
        a2 += Hs[(size_t)s6 * 64 + lane];
        a3 += Hs[(size_t)s7 * 64 + lane];
    }
    for (; j < end; ++j) a0 += Hs[(size_t)srcS[j] * 64 + lane];
    float v = ((a0 + a1) + (a2 + a3)) * dinv[wave] + bias[lane];
    if (do_relu) v = fmaxf(v, 0.f);
    Out[(size_t)wave * 64 + lane] = v;
}

// ---------------- aggregate 6 feats + bias + log_softmax: wave per node ----------------
__global__ __launch_bounds__(256) void agg6_lsm_kernel(
    const float* __restrict__ Hs6, const float* __restrict__ dinv,
    const int* __restrict__ srcS, const int* __restrict__ rowbeg,
    const int* __restrict__ rowend, const float* __restrict__ bias,
    float* __restrict__ out, int n) {
    const int wave = (blockIdx.x * blockDim.x + threadIdx.x) >> 6;
    const int lane = threadIdx.x & 63;
    if (wave >= n) return;
    const int slot = lane >> 3, f = lane & 7;  // 8 edges x 8 feats
    const int beg = rowbeg[wave], end = rowend[wave];
    float part = 0.f;
    for (int j0 = beg; j0 < end; j0 += 8) {
        int j = j0 + slot;
        if (j < end) {
            int s = srcS[j];
            part += Hs6[(size_t)s * 8 + f];  // 32B contiguous per edge
        }
    }
    // reduce over the 8 edge-slots (lane bits 3..5)
    part += __shfl_xor(part, 8);
    part += __shfl_xor(part, 16);
    part += __shfl_xor(part, 32);
    float bi = (f < 6) ? bias[f] : 0.f;
    float a = (part + Hs6[(size_t)wave * 8 + f]) * dinv[wave] + bi;
    // log_softmax over f=0..5 (lane bits 0..2)
    float am = (f < 6) ? a : -1e30f;
    float m = am;
    m = fmaxf(m, __shfl_xor(m, 1));
    m = fmaxf(m, __shfl_xor(m, 2));
    m = fmaxf(m, __shfl_xor(m, 4));
    float ex = (f < 6) ? expf(a - m) : 0.f;
    float sum = ex;
    sum += __shfl_xor(sum, 1);
    sum += __shfl_xor(sum, 2);
    sum += __shfl_xor(sum, 4);
    float lse = m + logf(sum);
    if (slot == 0 && f < 6) out[(size_t)wave * 6 + f] = a - lse;
}

// ---------------------------------------------------------------------------
extern "C" void kernel_launch(void* const* d_in, const int* in_sizes, int n_in,
                              void* d_out, int out_size, void* d_ws, size_t ws_size,
                              hipStream_t stream) {
    const float* x  = (const float*)d_in[0];
    const int*   ei = (const int*)d_in[1];
    const float* W1 = (const float*)d_in[2];
    const float* b1 = (const float*)d_in[3];
    const float* W2 = (const float*)d_in[4];
    const float* b2 = (const float*)d_in[5];
    const float* W3 = (const float*)d_in[6];
    const float* b3 = (const float*)d_in[7];
    float* out = (float*)d_out;

    const int n = in_sizes[0] / 128;  // 100000
    const int E = in_sizes[1] / 2;    // 3200000
    const int* src = ei;
    const int* dst = ei + E;
    const int NB = (n + BSZ - 1) / BSZ;  // 1563

    // ---- workspace carve ----
    char* ws = (char*)d_ws;
    auto carve = [&](size_t bytes) { char* p = ws; ws += WS_ALIGN(bytes); return p; };
    int*   cur    = (int*)  carve((size_t)NB * 4);
    float* dinv   = (float*)carve((size_t)n * 4);
    int*   slab   = (int*)  carve((size_t)NB * CAP * 4);   // 16.8 MB
    int*   srcS   = (int*)  carve((size_t)NB * CAP * 4);   // 16.8 MB
    int*   rowbeg = (int*)  carve((size_t)n * 4);
    int*   rowend = (int*)  carve((size_t)n * 4);
    float* bufA   = (float*)carve((size_t)n * 64 * 4);     // 25.6 MB
    float* bufB   = (float*)carve((size_t)n * 64 * 4);     // 25.6 MB
    float* bufC   = (float*)carve((size_t)n * 8 * 4);      // 3.2 MB (8-padded)
    (void)ws_size; (void)n_in; (void)out_size;

    // ---- build CSR (ws re-poisoned every call) ----
    hipMemsetAsync(cur, 0, (size_t)NB * 4, stream);
    bin_kernel<<<(E + BIN_CHUNK - 1) / BIN_CHUNK, 256, 0, stream>>>(src, dst, cur, slab, E, NB);
    bucket_sort_kernel<<<NB, 256, 0, stream>>>(slab, cur, srcS, rowbeg, rowend, dinv, n);

    const int aggGrid = (n + 3) / 4;  // wave per node, 4 waves/WG

    // ---- layer 1 ----
    linear_kernel<128><<<2048, 256, 0, stream>>>(x, W1, dinv, bufA, n);
    agg64_kernel<<<aggGrid, 256, 0, stream>>>(bufA, dinv, srcS, rowbeg, rowend, b1, bufB, n, 1);

    // ---- layer 2 ----
    linear_kernel<64><<<2048, 256, 0, stream>>>(bufB, W2, dinv, bufA, n);
    agg64_kernel<<<aggGrid, 256, 0, stream>>>(bufA, dinv, srcS, rowbeg, rowend, b2, bufB, n, 1);

    // ---- layer 3 ----
    linear3_kernel<<<2048, 256, 0, stream>>>(bufB, W3, dinv, bufC, n);
    agg6_lsm_kernel<<<aggGrid, 256, 0, stream>>>(bufC, dinv, srcS, rowbeg, rowend, b3, out, n);
}

// Round 5
// 512.520 us; speedup vs baseline: 6.4144x; 1.1526x over previous
//
#include <hip/hip_runtime.h>
#include <hip/hip_fp16.h>
#include <math.h>

// ---------------------------------------------------------------------------
// GCN 3-layer forward, round 5.
// out[i] = dinv[i] * ( sum_{e:dst=i} Hs[src] + Hs[i] ) + b,  Hs = (X@W)*dinv.
// Round-5 delta: Hs message buffers stored fp16 (halves gather bytes: 128B
// rows, 2 cache lines/edge). agg64 processes 2 edges/wave via half2 loads
// (32 lanes x 4B per edge), fp32 accumulation, shfl_xor(32) pair fold.
// Build (bin -> per-bucket counting sort -> CSR) unchanged from round 4.
// ---------------------------------------------------------------------------

#define WS_ALIGN(x) (((x) + 255) & ~(size_t)255)
#define BSZ 64        // nodes per bucket
#define CAP 2688      // slab capacity per bucket (mean 2048; +14 sigma)
#define EPT 16        // edges per thread in bin kernel
#define BIN_CHUNK (256 * EPT)

// ---------------- binning: LDS-staged chunked scatter ----------------
__global__ __launch_bounds__(256) void bin_kernel(
    const int* __restrict__ src, const int* __restrict__ dst,
    int* __restrict__ cur, int* __restrict__ slab, int E, int NB) {
    __shared__ int counts[1600];  // NB <= 1563
    const int tid = threadIdx.x;
    const int base = blockIdx.x * BIN_CHUNK;
    for (int i = tid; i < NB; i += 256) counts[i] = 0;
    __syncthreads();
    int b[EPT], w[EPT], lpos[EPT];
    #pragma unroll
    for (int k = 0; k < EPT; ++k) {
        int e = base + k * 256 + tid;
        if (e < E) {
            int s = src[e], d = dst[e];
            b[k] = d >> 6;
            w[k] = (s << 6) | (d & 63);
        } else b[k] = -1;
    }
    #pragma unroll
    for (int k = 0; k < EPT; ++k)
        if (b[k] >= 0) lpos[k] = atomicAdd(&counts[b[k]], 1);
    __syncthreads();
    for (int i = tid; i < NB; i += 256) {
        int c = counts[i];
        counts[i] = c ? atomicAdd(&cur[i], c) : 0;
    }
    __syncthreads();
    #pragma unroll
    for (int k = 0; k < EPT; ++k) {
        if (b[k] >= 0) {
            int pos = counts[b[k]] + lpos[k];
            if (pos < CAP) slab[(size_t)b[k] * CAP + pos] = w[k];
        }
    }
}

// ---------------- per-bucket counting sort -> per-node CSR + dinv ----------------
__global__ __launch_bounds__(256) void bucket_sort_kernel(
    const int* __restrict__ slab, const int* __restrict__ cur,
    int* __restrict__ srcS, int* __restrict__ rowbeg, int* __restrict__ rowend,
    float* __restrict__ dinv, int n) {
    __shared__ int cnt[BSZ], ofs[BSZ];
    const int b = blockIdx.x, tid = threadIdx.x;
    const int m = min(cur[b], CAP);
    const int* sp = slab + (size_t)b * CAP;
    if (tid < BSZ) cnt[tid] = 0;
    __syncthreads();
    for (int j = tid; j < m; j += 256) atomicAdd(&cnt[sp[j] & 63], 1);
    __syncthreads();
    if (tid == 0) {
        int run = 0;
        for (int r = 0; r < BSZ; ++r) { ofs[r] = run; run += cnt[r]; }
    }
    __syncthreads();
    if (tid < BSZ) {
        int node = b * BSZ + tid;
        if (node < n) {
            rowbeg[node] = b * CAP + ofs[tid];
            rowend[node] = b * CAP + ofs[tid] + cnt[tid];
            dinv[node] = rsqrtf((float)(cnt[tid] + 1));  // +1 self loop
        }
    }
    __syncthreads();
    if (tid < BSZ) cnt[tid] = ofs[tid];  // reuse as write cursors
    __syncthreads();
    for (int j = tid; j < m; j += 256) {
        int w = sp[j];
        int p = atomicAdd(&cnt[w & 63], 1);
        srcS[(size_t)b * CAP + p] = w >> 6;  // writes land in an 8KB window
    }
}

// ---------------- linear: Y16[n][64] = fp16( (X[n][K] @ W[K][64]) * dinv ) ----------------
template <int K>
__global__ __launch_bounds__(256) void linear_kernel(const float* __restrict__ X,
                                                     const float* __restrict__ W,
                                                     const float* __restrict__ dinv,
                                                     __half* __restrict__ Y, int n) {
    __shared__ float Wl[K * 64];
    __shared__ float Xs[4][K];
    const int tid = threadIdx.x;
    for (int i = tid; i < K * 64; i += 256) Wl[i] = W[i];
    const int feat = tid & 63;
    const int sub = tid >> 6;
    for (int base = blockIdx.x * 4; base < n; base += gridDim.x * 4) {
        __syncthreads();
        for (int i = tid; i < 4 * K; i += 256) {
            int r = i / K, c = i % K;
            int node = base + r;
            Xs[r][c] = (node < n) ? X[(size_t)node * K + c] : 0.f;
        }
        __syncthreads();
        int node = base + sub;
        if (node < n) {
            float acc = 0.f;
            #pragma unroll
            for (int k = 0; k < K; ++k) acc = fmaf(Xs[sub][k], Wl[k * 64 + feat], acc);
            Y[(size_t)node * 64 + feat] = __float2half_rn(acc * dinv[node]);
        }
    }
}

// ---------------- linear3: Y16[n][8] = fp16(pad8((X@W3)*dinv)) ----------------
__global__ __launch_bounds__(256) void linear3_kernel(const float* __restrict__ X,
                                                      const float* __restrict__ W,
                                                      const float* __restrict__ dinv,
                                                      __half* __restrict__ Y, int n) {
    __shared__ float Wl[64 * 6];
    __shared__ float Xs[32][65];
    const int tid = threadIdx.x;
    for (int i = tid; i < 64 * 6; i += 256) Wl[i] = W[i];
    const int sub = tid >> 3;   // 32 nodes per block
    const int feat = tid & 7;   // 8 slots, 6 active
    for (int base = blockIdx.x * 32; base < n; base += gridDim.x * 32) {
        __syncthreads();
        for (int i = tid; i < 32 * 64; i += 256) {
            int r = i >> 6, c = i & 63;
            int node = base + r;
            Xs[r][c] = (node < n) ? X[(size_t)node * 64 + c] : 0.f;
        }
        __syncthreads();
        int node = base + sub;
        if (node < n) {
            float r = 0.f;
            if (feat < 6) {
                float acc = 0.f;
                #pragma unroll
                for (int k = 0; k < 64; ++k) acc = fmaf(Xs[sub][k], Wl[k * 6 + feat], acc);
                r = acc * dinv[node];
            }
            Y[(size_t)node * 8 + feat] = __float2half_rn(r);  // pad feats 6,7 = 0
        }
    }
}

// ---------------- aggregate 64 feats: wave per node, 2 edges/iter, fp16 in ----------------
__global__ __launch_bounds__(256) void agg64_kernel(
    const __half2* __restrict__ Hs2, const float* __restrict__ dinv,
    const int* __restrict__ srcS, const int* __restrict__ rowbeg,
    const int* __restrict__ rowend, const float* __restrict__ bias,
    float* __restrict__ Out, int n, int do_relu) {
    const int wave = (blockIdx.x * blockDim.x + threadIdx.x) >> 6;
    const int lane = threadIdx.x & 63;
    if (wave >= n) return;
    const int hf = lane >> 5;   // which edge of the pair
    const int l = lane & 31;    // half2 index in row (feats 2l, 2l+1)
    const int beg = rowbeg[wave], end = rowend[wave];
    float ax0 = 0.f, ay0 = 0.f, ax1 = 0.f, ay1 = 0.f;
    float ax2 = 0.f, ay2 = 0.f, ax3 = 0.f, ay3 = 0.f;
    int j = beg;
    for (; j + 8 <= end; j += 8) {          // 8 edges: 4 per 32-lane half
        int s0 = srcS[j     + hf];
        int s1 = srcS[j + 2 + hf];
        int s2 = srcS[j + 4 + hf];
        int s3 = srcS[j + 6 + hf];
        float2 v0 = __half22float2(Hs2[(size_t)s0 * 32 + l]);
        float2 v1 = __half22float2(Hs2[(size_t)s1 * 32 + l]);
        float2 v2 = __half22float2(Hs2[(size_t)s2 * 32 + l]);
        float2 v3 = __half22float2(Hs2[(size_t)s3 * 32 + l]);
        ax0 += v0.x; ay0 += v0.y;
        ax1 += v1.x; ay1 += v1.y;
        ax2 += v2.x; ay2 += v2.y;
        ax3 += v3.x; ay3 += v3.y;
    }
    for (; j < end; j += 2) {               // tail, 2 edges at a time
        int jj = j + hf;
        if (jj < end) {
            float2 v = __half22float2(Hs2[(size_t)srcS[jj] * 32 + l]);
            ax0 += v.x; ay0 += v.y;
        }
    }
    float accx = (ax0 + ax1) + (ax2 + ax3);
    float accy = (ay0 + ay1) + (ay2 + ay3);
    accx += __shfl_xor(accx, 32);           // fold the two edge-halves
    accy += __shfl_xor(accy, 32);
    float2 self = __half22float2(Hs2[(size_t)wave * 32 + l]);
    const float di = dinv[wave];
    const float2 bi = *(const float2*)&bias[2 * l];
    float vx = (accx + self.x) * di + bi.x;
    float vy = (accy + self.y) * di + bi.y;
    if (do_relu) { vx = fmaxf(vx, 0.f); vy = fmaxf(vy, 0.f); }
    if (hf == 0) *(float2*)&Out[(size_t)wave * 64 + 2 * l] = make_float2(vx, vy);
}

// ---------------- aggregate 6 feats + bias + log_softmax: wave per node ----------------
__global__ __launch_bounds__(256) void agg6_lsm_kernel(
    const __half* __restrict__ Hs6, const float* __restrict__ dinv,
    const int* __restrict__ srcS, const int* __restrict__ rowbeg,
    const int* __restrict__ rowend, const float* __restrict__ bias,
    float* __restrict__ out, int n) {
    const int wave = (blockIdx.x * blockDim.x + threadIdx.x) >> 6;
    const int lane = threadIdx.x & 63;
    if (wave >= n) return;
    const int slot = lane >> 3, f = lane & 7;  // 8 edges x 8 feats
    const int beg = rowbeg[wave], end = rowend[wave];
    float part = 0.f;
    for (int j0 = beg; j0 < end; j0 += 8) {
        int j = j0 + slot;
        if (j < end) part += __half2float(Hs6[(size_t)srcS[j] * 8 + f]);  // 16B/edge
    }
    part += __shfl_xor(part, 8);
    part += __shfl_xor(part, 16);
    part += __shfl_xor(part, 32);
    float bi = (f < 6) ? bias[f] : 0.f;
    float a = (part + __half2float(Hs6[(size_t)wave * 8 + f])) * dinv[wave] + bi;
    float am = (f < 6) ? a : -1e30f;
    float m = am;
    m = fmaxf(m, __shfl_xor(m, 1));
    m = fmaxf(m, __shfl_xor(m, 2));
    m = fmaxf(m, __shfl_xor(m, 4));
    float ex = (f < 6) ? expf(a - m) : 0.f;
    float sum = ex;
    sum += __shfl_xor(sum, 1);
    sum += __shfl_xor(sum, 2);
    sum += __shfl_xor(sum, 4);
    float lse = m + logf(sum);
    if (slot == 0 && f < 6) out[(size_t)wave * 6 + f] = a - lse;
}

// ---------------------------------------------------------------------------
extern "C" void kernel_launch(void* const* d_in, const int* in_sizes, int n_in,
                              void* d_out, int out_size, void* d_ws, size_t ws_size,
                              hipStream_t stream) {
    const float* x  = (const float*)d_in[0];
    const int*   ei = (const int*)d_in[1];
    const float* W1 = (const float*)d_in[2];
    const float* b1 = (const float*)d_in[3];
    const float* W2 = (const float*)d_in[4];
    const float* b2 = (const float*)d_in[5];
    const float* W3 = (const float*)d_in[6];
    const float* b3 = (const float*)d_in[7];
    float* out = (float*)d_out;

    const int n = in_sizes[0] / 128;  // 100000
    const int E = in_sizes[1] / 2;    // 3200000
    const int* src = ei;
    const int* dst = ei + E;
    const int NB = (n + BSZ - 1) / BSZ;  // 1563

    // ---- workspace carve ----
    char* ws = (char*)d_ws;
    auto carve = [&](size_t bytes) { char* p = ws; ws += WS_ALIGN(bytes); return p; };
    int*    cur    = (int*)   carve((size_t)NB * 4);
    float*  dinv   = (float*) carve((size_t)n * 4);
    int*    slab   = (int*)   carve((size_t)NB * CAP * 4);   // 16.8 MB
    int*    srcS   = (int*)   carve((size_t)NB * CAP * 4);   // 16.8 MB
    int*    rowbeg = (int*)   carve((size_t)n * 4);
    int*    rowend = (int*)   carve((size_t)n * 4);
    __half* hsA    = (__half*)carve((size_t)n * 64 * 2);     // 12.8 MB (fp16 messages)
    float*  bufB   = (float*) carve((size_t)n * 64 * 4);     // 25.6 MB (agg out)
    __half* hsC    = (__half*)carve((size_t)n * 8 * 2);      // 1.6 MB (8-padded fp16)
    (void)ws_size; (void)n_in; (void)out_size;

    // ---- build CSR (ws re-poisoned every call) ----
    hipMemsetAsync(cur, 0, (size_t)NB * 4, stream);
    bin_kernel<<<(E + BIN_CHUNK - 1) / BIN_CHUNK, 256, 0, stream>>>(src, dst, cur, slab, E, NB);
    bucket_sort_kernel<<<NB, 256, 0, stream>>>(slab, cur, srcS, rowbeg, rowend, dinv, n);

    const int aggGrid = (n + 3) / 4;  // wave per node, 4 waves/WG

    // ---- layer 1 ----
    linear_kernel<128><<<2048, 256, 0, stream>>>(x, W1, dinv, hsA, n);
    agg64_kernel<<<aggGrid, 256, 0, stream>>>((const __half2*)hsA, dinv, srcS, rowbeg, rowend, b1, bufB, n, 1);

    // ---- layer 2 ----
    linear_kernel<64><<<2048, 256, 0, stream>>>(bufB, W2, dinv, hsA, n);
    agg64_kernel<<<aggGrid, 256, 0, stream>>>((const __half2*)hsA, dinv, srcS, rowbeg, rowend, b2, bufB, n, 1);

    // ---- layer 3 ----
    linear3_kernel<<<2048, 256, 0, stream>>>(bufB, W3, dinv, hsC, n);
    agg6_lsm_kernel<<<aggGrid, 256, 0, stream>>>(hsC, dinv, srcS, rowbeg, rowend, b3, out, n);
}

// Round 6
// 439.807 us; speedup vs baseline: 7.4749x; 1.1653x over previous
//
#include <hip/hip_runtime.h>
#include <hip/hip_fp16.h>
#include <math.h>

// ---------------------------------------------------------------------------
// GCN 3-layer forward, round 6.
// out[i] = dinv[i] * ( sum_{e:dst=i} Hs[src] + Hs[i] ) + b,  Hs = (X@W)*dinv.
// Round-6 delta: linear layers use MFMA f16 (16x16x32), X/W quantized fp16,
// fp32 accumulation. W pre-swizzled to B-fragment order in LDS (ds_read_b128).
// agg64 now writes fp16 so the next linear consumes fp16 directly.
// Build (bin -> per-bucket counting sort -> CSR) unchanged.
// ---------------------------------------------------------------------------

#define WS_ALIGN(x) (((x) + 255) & ~(size_t)255)
#define BSZ 64
#define CAP 2688
#define EPT 16
#define BIN_CHUNK (256 * EPT)

typedef _Float16 half8 __attribute__((ext_vector_type(8)));
typedef float floatx4 __attribute__((ext_vector_type(4)));

// ---------------- binning: LDS-staged chunked scatter ----------------
__global__ __launch_bounds__(256) void bin_kernel(
    const int* __restrict__ src, const int* __restrict__ dst,
    int* __restrict__ cur, int* __restrict__ slab, int E, int NB) {
    __shared__ int counts[1600];  // NB <= 1563
    const int tid = threadIdx.x;
    const int base = blockIdx.x * BIN_CHUNK;
    for (int i = tid; i < NB; i += 256) counts[i] = 0;
    __syncthreads();
    int b[EPT], w[EPT], lpos[EPT];
    #pragma unroll
    for (int k = 0; k < EPT; ++k) {
        int e = base + k * 256 + tid;
        if (e < E) {
            int s = src[e], d = dst[e];
            b[k] = d >> 6;
            w[k] = (s << 6) | (d & 63);
        } else b[k] = -1;
    }
    #pragma unroll
    for (int k = 0; k < EPT; ++k)
        if (b[k] >= 0) lpos[k] = atomicAdd(&counts[b[k]], 1);
    __syncthreads();
    for (int i = tid; i < NB; i += 256) {
        int c = counts[i];
        counts[i] = c ? atomicAdd(&cur[i], c) : 0;
    }
    __syncthreads();
    #pragma unroll
    for (int k = 0; k < EPT; ++k) {
        if (b[k] >= 0) {
            int pos = counts[b[k]] + lpos[k];
            if (pos < CAP) slab[(size_t)b[k] * CAP + pos] = w[k];
        }
    }
}

// ---------------- per-bucket counting sort -> per-node CSR + dinv ----------------
__global__ __launch_bounds__(256) void bucket_sort_kernel(
    const int* __restrict__ slab, const int* __restrict__ cur,
    int* __restrict__ srcS, int* __restrict__ rowbeg, int* __restrict__ rowend,
    float* __restrict__ dinv, int n) {
    __shared__ int cnt[BSZ], ofs[BSZ];
    const int b = blockIdx.x, tid = threadIdx.x;
    const int m = min(cur[b], CAP);
    const int* sp = slab + (size_t)b * CAP;
    if (tid < BSZ) cnt[tid] = 0;
    __syncthreads();
    for (int j = tid; j < m; j += 256) atomicAdd(&cnt[sp[j] & 63], 1);
    __syncthreads();
    if (tid == 0) {
        int run = 0;
        for (int r = 0; r < BSZ; ++r) { ofs[r] = run; run += cnt[r]; }
    }
    __syncthreads();
    if (tid < BSZ) {
        int node = b * BSZ + tid;
        if (node < n) {
            rowbeg[node] = b * CAP + ofs[tid];
            rowend[node] = b * CAP + ofs[tid] + cnt[tid];
            dinv[node] = rsqrtf((float)(cnt[tid] + 1));  // +1 self loop
        }
    }
    __syncthreads();
    if (tid < BSZ) cnt[tid] = ofs[tid];
    __syncthreads();
    for (int j = tid; j < m; j += 256) {
        int w = sp[j];
        int p = atomicAdd(&cnt[w & 63], 1);
        srcS[(size_t)b * CAP + p] = w >> 6;
    }
}

// ---------------- fp32 -> fp16 convert (x once per call) ----------------
__global__ __launch_bounds__(256) void cvt_kernel(const float4* __restrict__ X,
                                                  uint2* __restrict__ Y, int n4) {
    int i = blockIdx.x * blockDim.x + threadIdx.x;
    if (i >= n4) return;
    float4 v = X[i];
    __half2 a = __floats2half2_rn(v.x, v.y);
    __half2 b = __floats2half2_rn(v.z, v.w);
    uint2 o;
    o.x = *(const unsigned int*)&a;
    o.y = *(const unsigned int*)&b;
    Y[i] = o;
}

// ---------------- MFMA linear: Y16[n][64] = fp16( (Xh[n][K] @ W[K][64]) * dinv ) ----
// WG = 4 waves; wave w computes nodes [base + 16w, base + 16w + 16) x 64 feats.
// mfma_f32_16x16x32_f16: A[m=lane&15][k=(lane>>4)*8+j], B[k=(lane>>4)*8+j][c=lane&15],
// C/D: col=lane&15, row=(lane>>4)*4+reg.
template <int K>
__global__ __launch_bounds__(256) void linear_mfma_kernel(
    const _Float16* __restrict__ Xh, const float* __restrict__ W,
    const float* __restrict__ dinv, _Float16* __restrict__ Y, int n) {
    constexpr int KC = K / 32;
    __shared__ _Float16 Bf[KC * 4 * 64 * 8];  // B-fragment order; K=128 -> 16KB
    const int tid = threadIdx.x;
    // build B-fragments: Bf[kc][tile][lane][j] = W[kc*32+(lane>>4)*8+j][tile*16+(lane&15)]
    for (int i = tid; i < KC * 4 * 64 * 8; i += 256) {
        int j = i & 7, lane = (i >> 3) & 63, tile = (i >> 9) & 3, kc = i >> 11;
        int k = kc * 32 + ((lane >> 4) << 3) + j;
        int col = tile * 16 + (lane & 15);
        Bf[i] = (_Float16)W[k * 64 + col];
    }
    __syncthreads();
    const int lane = tid & 63, wid = tid >> 6;
    const int base = blockIdx.x * 64 + wid * 16;
    if (base >= n) return;
    const int mrow = lane & 15, quad = lane >> 4;
    const int anode = min(base + mrow, n - 1);  // clamp: OOB rows unwritten
    floatx4 acc[4] = {{0, 0, 0, 0}, {0, 0, 0, 0}, {0, 0, 0, 0}, {0, 0, 0, 0}};
    #pragma unroll
    for (int kc = 0; kc < KC; ++kc) {
        half8 a = *(const half8*)&Xh[(size_t)anode * K + kc * 32 + quad * 8];
        #pragma unroll
        for (int t = 0; t < 4; ++t) {
            half8 b = *(const half8*)&Bf[((kc * 4 + t) * 64 + lane) * 8];
            acc[t] = __builtin_amdgcn_mfma_f32_16x16x32_f16(a, b, acc[t], 0, 0, 0);
        }
    }
    #pragma unroll
    for (int r = 0; r < 4; ++r) {
        int node = base + quad * 4 + r;
        if (node < n) {
            float di = dinv[node];
            #pragma unroll
            for (int t = 0; t < 4; ++t)
                Y[(size_t)node * 64 + t * 16 + mrow] = (_Float16)(acc[t][r] * di);
        }
    }
}

// ---------------- linear3: Y16[n][8] = fp16(pad8((Xh@W3)*dinv)), fp16 input ----------------
__global__ __launch_bounds__(256) void linear3_kernel(const __half* __restrict__ Xh,
                                                      const float* __restrict__ W,
                                                      const float* __restrict__ dinv,
                                                      __half* __restrict__ Y, int n) {
    __shared__ float Wl[64 * 6];
    __shared__ float Xs[32][65];
    const int tid = threadIdx.x;
    for (int i = tid; i < 64 * 6; i += 256) Wl[i] = W[i];
    const int sub = tid >> 3;
    const int feat = tid & 7;
    for (int base = blockIdx.x * 32; base < n; base += gridDim.x * 32) {
        __syncthreads();
        for (int i = tid; i < 32 * 64; i += 256) {
            int r = i >> 6, c = i & 63;
            int node = base + r;
            Xs[r][c] = (node < n) ? __half2float(Xh[(size_t)node * 64 + c]) : 0.f;
        }
        __syncthreads();
        int node = base + sub;
        if (node < n) {
            float r = 0.f;
            if (feat < 6) {
                float acc = 0.f;
                #pragma unroll
                for (int k = 0; k < 64; ++k) acc = fmaf(Xs[sub][k], Wl[k * 6 + feat], acc);
                r = acc * dinv[node];
            }
            Y[(size_t)node * 8 + feat] = __float2half_rn(r);
        }
    }
}

// ---------------- aggregate 64 feats: wave per node, fp16 in, fp16 out ----------------
__global__ __launch_bounds__(256) void agg64_kernel(
    const __half2* __restrict__ Hs2, const float* __restrict__ dinv,
    const int* __restrict__ srcS, const int* __restrict__ rowbeg,
    const int* __restrict__ rowend, const float* __restrict__ bias,
    __half2* __restrict__ Out, int n, int do_relu) {
    const int wave = (blockIdx.x * blockDim.x + threadIdx.x) >> 6;
    const int lane = threadIdx.x & 63;
    if (wave >= n) return;
    const int hf = lane >> 5;   // which edge of the pair
    const int l = lane & 31;    // half2 index in row (feats 2l, 2l+1)
    const int beg = rowbeg[wave], end = rowend[wave];
    float ax0 = 0.f, ay0 = 0.f, ax1 = 0.f, ay1 = 0.f;
    float ax2 = 0.f, ay2 = 0.f, ax3 = 0.f, ay3 = 0.f;
    int j = beg;
    for (; j + 8 <= end; j += 8) {
        int s0 = srcS[j     + hf];
        int s1 = srcS[j + 2 + hf];
        int s2 = srcS[j + 4 + hf];
        int s3 = srcS[j + 6 + hf];
        float2 v0 = __half22float2(Hs2[(size_t)s0 * 32 + l]);
        float2 v1 = __half22float2(Hs2[(size_t)s1 * 32 + l]);
        float2 v2 = __half22float2(Hs2[(size_t)s2 * 32 + l]);
        float2 v3 = __half22float2(Hs2[(size_t)s3 * 32 + l]);
        ax0 += v0.x; ay0 += v0.y;
        ax1 += v1.x; ay1 += v1.y;
        ax2 += v2.x; ay2 += v2.y;
        ax3 += v3.x; ay3 += v3.y;
    }
    for (; j < end; j += 2) {
        int jj = j + hf;
        if (jj < end) {
            float2 v = __half22float2(Hs2[(size_t)srcS[jj] * 32 + l]);
            ax0 += v.x; ay0 += v.y;
        }
    }
    float accx = (ax0 + ax1) + (ax2 + ax3);
    float accy = (ay0 + ay1) + (ay2 + ay3);
    accx += __shfl_xor(accx, 32);
    accy += __shfl_xor(accy, 32);
    float2 self = __half22float2(Hs2[(size_t)wave * 32 + l]);
    const float di = dinv[wave];
    const float2 bi = *(const float2*)&bias[2 * l];
    float vx = (accx + self.x) * di + bi.x;
    float vy = (accy + self.y) * di + bi.y;
    if (do_relu) { vx = fmaxf(vx, 0.f); vy = fmaxf(vy, 0.f); }
    if (hf == 0) Out[(size_t)wave * 32 + l] = __floats2half2_rn(vx, vy);
}

// ---------------- aggregate 6 feats + bias + log_softmax ----------------
__global__ __launch_bounds__(256) void agg6_lsm_kernel(
    const __half* __restrict__ Hs6, const float* __restrict__ dinv,
    const int* __restrict__ srcS, const int* __restrict__ rowbeg,
    const int* __restrict__ rowend, const float* __restrict__ bias,
    float* __restrict__ out, int n) {
    const int wave = (blockIdx.x * blockDim.x + threadIdx.x) >> 6;
    const int lane = threadIdx.x & 63;
    if (wave >= n) return;
    const int slot = lane >> 3, f = lane & 7;
    const int beg = rowbeg[wave], end = rowend[wave];
    float part = 0.f;
    for (int j0 = beg; j0 < end; j0 += 8) {
        int j = j0 + slot;
        if (j < end) part += __half2float(Hs6[(size_t)srcS[j] * 8 + f]);
    }
    part += __shfl_xor(part, 8);
    part += __shfl_xor(part, 16);
    part += __shfl_xor(part, 32);
    float bi = (f < 6) ? bias[f] : 0.f;
    float a = (part + __half2float(Hs6[(size_t)wave * 8 + f])) * dinv[wave] + bi;
    float am = (f < 6) ? a : -1e30f;
    float m = am;
    m = fmaxf(m, __shfl_xor(m, 1));
    m = fmaxf(m, __shfl_xor(m, 2));
    m = fmaxf(m, __shfl_xor(m, 4));
    float ex = (f < 6) ? expf(a - m) : 0.f;
    float sum = ex;
    sum += __shfl_xor(sum, 1);
    sum += __shfl_xor(sum, 2);
    sum += __shfl_xor(sum, 4);
    float lse = m + logf(sum);
    if (slot == 0 && f < 6) out[(size_t)wave * 6 + f] = a - lse;
}

// ---------------------------------------------------------------------------
extern "C" void kernel_launch(void* const* d_in, const int* in_sizes, int n_in,
                              void* d_out, int out_size, void* d_ws, size_t ws_size,
                              hipStream_t stream) {
    const float* x  = (const float*)d_in[0];
    const int*   ei = (const int*)d_in[1];
    const float* W1 = (const float*)d_in[2];
    const float* b1 = (const float*)d_in[3];
    const float* W2 = (const float*)d_in[4];
    const float* b2 = (const float*)d_in[5];
    const float* W3 = (const float*)d_in[6];
    const float* b3 = (const float*)d_in[7];
    float* out = (float*)d_out;

    const int n = in_sizes[0] / 128;  // 100000
    const int E = in_sizes[1] / 2;    // 3200000
    const int* src = ei;
    const int* dst = ei + E;
    const int NB = (n + BSZ - 1) / BSZ;  // 1563

    // ---- workspace carve ----
    char* ws = (char*)d_ws;
    auto carve = [&](size_t bytes) { char* p = ws; ws += WS_ALIGN(bytes); return p; };
    int*      cur    = (int*)     carve((size_t)NB * 4);
    float*    dinv   = (float*)   carve((size_t)n * 4);
    int*      slab   = (int*)     carve((size_t)NB * CAP * 4);   // 16.8 MB
    int*      srcS   = (int*)     carve((size_t)NB * CAP * 4);   // 16.8 MB
    int*      rowbeg = (int*)     carve((size_t)n * 4);
    int*      rowend = (int*)     carve((size_t)n * 4);
    _Float16* xh     = (_Float16*)carve((size_t)n * 128 * 2 + 4096);  // 25.6 MB (+pad)
    _Float16* hsA    = (_Float16*)carve((size_t)n * 64 * 2 + 4096);   // 12.8 MB
    _Float16* hsB    = (_Float16*)carve((size_t)n * 64 * 2 + 4096);   // 12.8 MB
    __half*   hsC    = (__half*)  carve((size_t)n * 8 * 2);           // 1.6 MB
    (void)ws_size; (void)n_in; (void)out_size;

    // ---- build CSR + fp16 input ----
    hipMemsetAsync(cur, 0, (size_t)NB * 4, stream);
    bin_kernel<<<(E + BIN_CHUNK - 1) / BIN_CHUNK, 256, 0, stream>>>(src, dst, cur, slab, E, NB);
    bucket_sort_kernel<<<NB, 256, 0, stream>>>(slab, cur, srcS, rowbeg, rowend, dinv, n);
    const int n4 = n * 128 / 4;
    cvt_kernel<<<(n4 + 255) / 256, 256, 0, stream>>>((const float4*)x, (uint2*)xh, n4);

    const int aggGrid = (n + 3) / 4;       // wave per node, 4 waves/WG
    const int linGrid = (n + 63) / 64;     // 64 nodes per WG

    // ---- layer 1 ----
    linear_mfma_kernel<128><<<linGrid, 256, 0, stream>>>(xh, W1, dinv, hsA, n);
    agg64_kernel<<<aggGrid, 256, 0, stream>>>((const __half2*)hsA, dinv, srcS, rowbeg, rowend, b1, (__half2*)hsB, n, 1);

    // ---- layer 2 ----
    linear_mfma_kernel<64><<<linGrid, 256, 0, stream>>>(hsB, W2, dinv, hsA, n);
    agg64_kernel<<<aggGrid, 256, 0, stream>>>((const __half2*)hsA, dinv, srcS, rowbeg, rowend, b2, (__half2*)hsB, n, 1);

    // ---- layer 3 ----
    linear3_kernel<<<2048, 256, 0, stream>>>((const __half*)hsB, W3, dinv, hsC, n);
    agg6_lsm_kernel<<<aggGrid, 256, 0, stream>>>(hsC, dinv, srcS, rowbeg, rowend, b3, out, n);
}

// Round 7
// 404.364 us; speedup vs baseline: 8.1301x; 1.0877x over previous
//
#include <hip/hip_runtime.h>
#include <hip/hip_fp16.h>
#include <math.h>

// ---------------------------------------------------------------------------
// GCN 3-layer forward, round 7.
// out[i] = dinv[i] * ( sum_{e:dst=i} Hs[src] + Hs[i] ) + b,  Hs = (X@W)*dinv.
// Round-7 delta:
//  - agg64: 8 lanes/edge x dwordx4 (half8) gathers -> 1 load inst per 8 edges,
//    fp32 accum 8 feats/lane, shfl_xor(8/16/32) slot fold, half8 store.
//  - linear_mfma<128> reads fp32 x directly (cvt in-register) -> cvt_kernel gone.
//  - bin_kernel: contiguous-per-thread edge loads (int4 x4).
// ---------------------------------------------------------------------------

#define WS_ALIGN(x) (((x) + 255) & ~(size_t)255)
#define BSZ 64
#define CAP 2688
#define EPT 16
#define BIN_CHUNK (256 * EPT)

typedef _Float16 half8 __attribute__((ext_vector_type(8)));
typedef float floatx4 __attribute__((ext_vector_type(4)));

// ---------------- binning: LDS-staged chunked scatter ----------------
__global__ __launch_bounds__(256) void bin_kernel(
    const int* __restrict__ src, const int* __restrict__ dst,
    int* __restrict__ cur, int* __restrict__ slab, int E, int NB) {
    __shared__ int counts[1600];  // NB <= 1563
    const int tid = threadIdx.x;
    const int base = blockIdx.x * BIN_CHUNK + tid * EPT;  // contiguous per thread
    for (int i = tid; i < NB; i += 256) counts[i] = 0;
    __syncthreads();
    int b[EPT], w[EPT], lpos[EPT];
    #pragma unroll
    for (int k = 0; k < EPT; ++k) {
        int e = base + k;
        if (e < E) {
            int s = src[e], d = dst[e];   // compiler: 4x int4 each
            b[k] = d >> 6;
            w[k] = (s << 6) | (d & 63);
        } else b[k] = -1;
    }
    #pragma unroll
    for (int k = 0; k < EPT; ++k)
        if (b[k] >= 0) lpos[k] = atomicAdd(&counts[b[k]], 1);
    __syncthreads();
    for (int i = tid; i < NB; i += 256) {
        int c = counts[i];
        counts[i] = c ? atomicAdd(&cur[i], c) : 0;
    }
    __syncthreads();
    #pragma unroll
    for (int k = 0; k < EPT; ++k) {
        if (b[k] >= 0) {
            int pos = counts[b[k]] + lpos[k];
            if (pos < CAP) slab[(size_t)b[k] * CAP + pos] = w[k];
        }
    }
}

// ---------------- per-bucket counting sort -> per-node CSR + dinv ----------------
__global__ __launch_bounds__(256) void bucket_sort_kernel(
    const int* __restrict__ slab, const int* __restrict__ cur,
    int* __restrict__ srcS, int* __restrict__ rowbeg, int* __restrict__ rowend,
    float* __restrict__ dinv, int n) {
    __shared__ int cnt[BSZ], ofs[BSZ];
    const int b = blockIdx.x, tid = threadIdx.x;
    const int m = min(cur[b], CAP);
    const int* sp = slab + (size_t)b * CAP;
    if (tid < BSZ) cnt[tid] = 0;
    __syncthreads();
    for (int j = tid; j < m; j += 256) atomicAdd(&cnt[sp[j] & 63], 1);
    __syncthreads();
    if (tid == 0) {
        int run = 0;
        for (int r = 0; r < BSZ; ++r) { ofs[r] = run; run += cnt[r]; }
    }
    __syncthreads();
    if (tid < BSZ) {
        int node = b * BSZ + tid;
        if (node < n) {
            rowbeg[node] = b * CAP + ofs[tid];
            rowend[node] = b * CAP + ofs[tid] + cnt[tid];
            dinv[node] = rsqrtf((float)(cnt[tid] + 1));  // +1 self loop
        }
    }
    __syncthreads();
    if (tid < BSZ) cnt[tid] = ofs[tid];
    __syncthreads();
    for (int j = tid; j < m; j += 256) {
        int w = sp[j];
        int p = atomicAdd(&cnt[w & 63], 1);
        srcS[(size_t)b * CAP + p] = w >> 6;
    }
}

// ---------------- MFMA linear (fp32 input): Y16 = fp16((Xf@W)*dinv) ----------------
// mfma_f32_16x16x32_f16: A[m=lane&15][k=(lane>>4)*8+j], C/D col=lane&15, row=quad*4+r.
template <int K>
__global__ __launch_bounds__(256) void linear_mfma_f32_kernel(
    const float* __restrict__ Xf, const float* __restrict__ W,
    const float* __restrict__ dinv, _Float16* __restrict__ Y, int n) {
    constexpr int KC = K / 32;
    __shared__ _Float16 Bf[KC * 4 * 64 * 8];  // B-fragment order; K=128 -> 16KB
    const int tid = threadIdx.x;
    for (int i = tid; i < KC * 4 * 64 * 8; i += 256) {
        int j = i & 7, lane = (i >> 3) & 63, tile = (i >> 9) & 3, kc = i >> 11;
        int k = kc * 32 + ((lane >> 4) << 3) + j;
        int col = tile * 16 + (lane & 15);
        Bf[i] = (_Float16)W[k * 64 + col];
    }
    __syncthreads();
    const int lane = tid & 63, wid = tid >> 6;
    const int base = blockIdx.x * 64 + wid * 16;
    if (base >= n) return;
    const int mrow = lane & 15, quad = lane >> 4;
    const int anode = min(base + mrow, n - 1);
    floatx4 acc[4] = {{0, 0, 0, 0}, {0, 0, 0, 0}, {0, 0, 0, 0}, {0, 0, 0, 0}};
    #pragma unroll
    for (int kc = 0; kc < KC; ++kc) {
        float4 xa = *(const float4*)&Xf[(size_t)anode * K + kc * 32 + quad * 8];
        float4 xb = *(const float4*)&Xf[(size_t)anode * K + kc * 32 + quad * 8 + 4];
        half8 a;
        a[0] = (_Float16)xa.x; a[1] = (_Float16)xa.y; a[2] = (_Float16)xa.z; a[3] = (_Float16)xa.w;
        a[4] = (_Float16)xb.x; a[5] = (_Float16)xb.y; a[6] = (_Float16)xb.z; a[7] = (_Float16)xb.w;
        #pragma unroll
        for (int t = 0; t < 4; ++t) {
            half8 b = *(const half8*)&Bf[((kc * 4 + t) * 64 + lane) * 8];
            acc[t] = __builtin_amdgcn_mfma_f32_16x16x32_f16(a, b, acc[t], 0, 0, 0);
        }
    }
    #pragma unroll
    for (int r = 0; r < 4; ++r) {
        int node = base + quad * 4 + r;
        if (node < n) {
            float di = dinv[node];
            #pragma unroll
            for (int t = 0; t < 4; ++t)
                Y[(size_t)node * 64 + t * 16 + mrow] = (_Float16)(acc[t][r] * di);
        }
    }
}

// ---------------- MFMA linear (fp16 input), K=64 ----------------
__global__ __launch_bounds__(256) void linear_mfma_f16_kernel(
    const _Float16* __restrict__ Xh, const float* __restrict__ W,
    const float* __restrict__ dinv, _Float16* __restrict__ Y, int n) {
    constexpr int K = 64, KC = 2;
    __shared__ _Float16 Bf[KC * 4 * 64 * 8];  // 8KB
    const int tid = threadIdx.x;
    for (int i = tid; i < KC * 4 * 64 * 8; i += 256) {
        int j = i & 7, lane = (i >> 3) & 63, tile = (i >> 9) & 3, kc = i >> 11;
        int k = kc * 32 + ((lane >> 4) << 3) + j;
        int col = tile * 16 + (lane & 15);
        Bf[i] = (_Float16)W[k * 64 + col];
    }
    __syncthreads();
    const int lane = tid & 63, wid = tid >> 6;
    const int base = blockIdx.x * 64 + wid * 16;
    if (base >= n) return;
    const int mrow = lane & 15, quad = lane >> 4;
    const int anode = min(base + mrow, n - 1);
    floatx4 acc[4] = {{0, 0, 0, 0}, {0, 0, 0, 0}, {0, 0, 0, 0}, {0, 0, 0, 0}};
    #pragma unroll
    for (int kc = 0; kc < KC; ++kc) {
        half8 a = *(const half8*)&Xh[(size_t)anode * K + kc * 32 + quad * 8];
        #pragma unroll
        for (int t = 0; t < 4; ++t) {
            half8 b = *(const half8*)&Bf[((kc * 4 + t) * 64 + lane) * 8];
            acc[t] = __builtin_amdgcn_mfma_f32_16x16x32_f16(a, b, acc[t], 0, 0, 0);
        }
    }
    #pragma unroll
    for (int r = 0; r < 4; ++r) {
        int node = base + quad * 4 + r;
        if (node < n) {
            float di = dinv[node];
            #pragma unroll
            for (int t = 0; t < 4; ++t)
                Y[(size_t)node * 64 + t * 16 + mrow] = (_Float16)(acc[t][r] * di);
        }
    }
}

// ---------------- linear3: Y16[n][8] = fp16(pad8((Xh@W3)*dinv)) ----------------
__global__ __launch_bounds__(256) void linear3_kernel(const __half* __restrict__ Xh,
                                                      const float* __restrict__ W,
                                                      const float* __restrict__ dinv,
                                                      __half* __restrict__ Y, int n) {
    __shared__ float Wl[64 * 6];
    __shared__ float Xs[32][65];
    const int tid = threadIdx.x;
    for (int i = tid; i < 64 * 6; i += 256) Wl[i] = W[i];
    const int sub = tid >> 3;
    const int feat = tid & 7;
    for (int base = blockIdx.x * 32; base < n; base += gridDim.x * 32) {
        __syncthreads();
        for (int i = tid; i < 32 * 64; i += 256) {
            int r = i >> 6, c = i & 63;
            int node = base + r;
            Xs[r][c] = (node < n) ? __half2float(Xh[(size_t)node * 64 + c]) : 0.f;
        }
        __syncthreads();
        int node = base + sub;
        if (node < n) {
            float r = 0.f;
            if (feat < 6) {
                float acc = 0.f;
                #pragma unroll
                for (int k = 0; k < 64; ++k) acc = fmaf(Xs[sub][k], Wl[k * 6 + feat], acc);
                r = acc * dinv[node];
            }
            Y[(size_t)node * 8 + feat] = __float2half_rn(r);
        }
    }
}

// ---------------- aggregate 64 feats: wave/node, 8 lanes/edge, half8 gathers ----------------
__global__ __launch_bounds__(256) void agg64_kernel(
    const _Float16* __restrict__ Hs, const float* __restrict__ dinv,
    const int* __restrict__ srcS, const int* __restrict__ rowbeg,
    const int* __restrict__ rowend, const float* __restrict__ bias,
    _Float16* __restrict__ Out, int n, int do_relu) {
    const int wave = (blockIdx.x * blockDim.x + threadIdx.x) >> 6;
    const int lane = threadIdx.x & 63;
    if (wave >= n) return;
    const int slot = lane >> 3;  // edge slot 0..7
    const int f8 = lane & 7;     // feat slice [f8*8, f8*8+8)
    const int beg = rowbeg[wave], end = rowend[wave];
    float acc[8] = {0.f, 0.f, 0.f, 0.f, 0.f, 0.f, 0.f, 0.f};
    int j = beg;
    for (; j + 16 <= end; j += 16) {      // 16 edges: 2 gathers in flight
        int sA = srcS[j + slot];
        int sB = srcS[j + 8 + slot];
        half8 vA = *(const half8*)&Hs[(size_t)sA * 64 + f8 * 8];
        half8 vB = *(const half8*)&Hs[(size_t)sB * 64 + f8 * 8];
        #pragma unroll
        for (int i = 0; i < 8; ++i) acc[i] += (float)vA[i] + (float)vB[i];
    }
    for (; j < end; j += 8) {             // tail, 8 edges (masked)
        int jj = j + slot;
        int s = srcS[min(jj, end - 1)];   // end>j>=0 here, so end-1 valid
        half8 v = *(const half8*)&Hs[(size_t)s * 64 + f8 * 8];
        float flag = (jj < end) ? 1.f : 0.f;
        #pragma unroll
        for (int i = 0; i < 8; ++i) acc[i] = fmaf((float)v[i], flag, acc[i]);
    }
    #pragma unroll
    for (int i = 0; i < 8; ++i) {         // fold the 8 edge slots
        acc[i] += __shfl_xor(acc[i], 8);
        acc[i] += __shfl_xor(acc[i], 16);
        acc[i] += __shfl_xor(acc[i], 32);
    }
    half8 self = *(const half8*)&Hs[(size_t)wave * 64 + f8 * 8];
    const float di = dinv[wave];
    float4 b0 = *(const float4*)&bias[f8 * 8];
    float4 b1 = *(const float4*)&bias[f8 * 8 + 4];
    float bb[8] = {b0.x, b0.y, b0.z, b0.w, b1.x, b1.y, b1.z, b1.w};
    half8 o;
    #pragma unroll
    for (int i = 0; i < 8; ++i) {
        float v = (acc[i] + (float)self[i]) * di + bb[i];
        if (do_relu) v = fmaxf(v, 0.f);
        o[i] = (_Float16)v;
    }
    if (slot == 0) *(half8*)&Out[(size_t)wave * 64 + f8 * 8] = o;
}

// ---------------- aggregate 6 feats + bias + log_softmax ----------------
__global__ __launch_bounds__(256) void agg6_lsm_kernel(
    const __half* __restrict__ Hs6, const float* __restrict__ dinv,
    const int* __restrict__ srcS, const int* __restrict__ rowbeg,
    const int* __restrict__ rowend, const float* __restrict__ bias,
    float* __restrict__ out, int n) {
    const int wave = (blockIdx.x * blockDim.x + threadIdx.x) >> 6;
    const int lane = threadIdx.x & 63;
    if (wave >= n) return;
    const int slot = lane >> 3, f = lane & 7;
    const int beg = rowbeg[wave], end = rowend[wave];
    float part = 0.f;
    for (int j0 = beg; j0 < end; j0 += 8) {
        int j = j0 + slot;
        if (j < end) part += __half2float(Hs6[(size_t)srcS[j] * 8 + f]);
    }
    part += __shfl_xor(part, 8);
    part += __shfl_xor(part, 16);
    part += __shfl_xor(part, 32);
    float bi = (f < 6) ? bias[f] : 0.f;
    float a = (part + __half2float(Hs6[(size_t)wave * 8 + f])) * dinv[wave] + bi;
    float am = (f < 6) ? a : -1e30f;
    float m = am;
    m = fmaxf(m, __shfl_xor(m, 1));
    m = fmaxf(m, __shfl_xor(m, 2));
    m = fmaxf(m, __shfl_xor(m, 4));
    float ex = (f < 6) ? expf(a - m) : 0.f;
    float sum = ex;
    sum += __shfl_xor(sum, 1);
    sum += __shfl_xor(sum, 2);
    sum += __shfl_xor(sum, 4);
    float lse = m + logf(sum);
    if (slot == 0 && f < 6) out[(size_t)wave * 6 + f] = a - lse;
}

// ---------------------------------------------------------------------------
extern "C" void kernel_launch(void* const* d_in, const int* in_sizes, int n_in,
                              void* d_out, int out_size, void* d_ws, size_t ws_size,
                              hipStream_t stream) {
    const float* x  = (const float*)d_in[0];
    const int*   ei = (const int*)d_in[1];
    const float* W1 = (const float*)d_in[2];
    const float* b1 = (const float*)d_in[3];
    const float* W2 = (const float*)d_in[4];
    const float* b2 = (const float*)d_in[5];
    const float* W3 = (const float*)d_in[6];
    const float* b3 = (const float*)d_in[7];
    float* out = (float*)d_out;

    const int n = in_sizes[0] / 128;  // 100000
    const int E = in_sizes[1] / 2;    // 3200000
    const int* src = ei;
    const int* dst = ei + E;
    const int NB = (n + BSZ - 1) / BSZ;  // 1563

    // ---- workspace carve ----
    char* ws = (char*)d_ws;
    auto carve = [&](size_t bytes) { char* p = ws; ws += WS_ALIGN(bytes); return p; };
    int*      cur    = (int*)     carve((size_t)NB * 4);
    float*    dinv   = (float*)   carve((size_t)n * 4);
    int*      slab   = (int*)     carve((size_t)NB * CAP * 4);   // 16.8 MB
    int*      srcS   = (int*)     carve((size_t)NB * CAP * 4);   // 16.8 MB
    int*      rowbeg = (int*)     carve((size_t)n * 4);
    int*      rowend = (int*)     carve((size_t)n * 4);
    _Float16* hsA    = (_Float16*)carve((size_t)n * 64 * 2 + 4096);   // 12.8 MB
    _Float16* hsB    = (_Float16*)carve((size_t)n * 64 * 2 + 4096);   // 12.8 MB
    __half*   hsC    = (__half*)  carve((size_t)n * 8 * 2);           // 1.6 MB
    (void)ws_size; (void)n_in; (void)out_size;

    // ---- build CSR ----
    hipMemsetAsync(cur, 0, (size_t)NB * 4, stream);
    bin_kernel<<<(E + BIN_CHUNK - 1) / BIN_CHUNK, 256, 0, stream>>>(src, dst, cur, slab, E, NB);
    bucket_sort_kernel<<<NB, 256, 0, stream>>>(slab, cur, srcS, rowbeg, rowend, dinv, n);

    const int aggGrid = (n + 3) / 4;       // wave per node, 4 waves/WG
    const int linGrid = (n + 63) / 64;     // 64 nodes per WG

    // ---- layer 1 ----
    linear_mfma_f32_kernel<128><<<linGrid, 256, 0, stream>>>(x, W1, dinv, hsA, n);
    agg64_kernel<<<aggGrid, 256, 0, stream>>>(hsA, dinv, srcS, rowbeg, rowend, b1, hsB, n, 1);

    // ---- layer 2 ----
    linear_mfma_f16_kernel<<<linGrid, 256, 0, stream>>>(hsB, W2, dinv, hsA, n);
    agg64_kernel<<<aggGrid, 256, 0, stream>>>(hsA, dinv, srcS, rowbeg, rowend, b2, hsB, n, 1);

    // ---- layer 3 ----
    linear3_kernel<<<2048, 256, 0, stream>>>((const __half*)hsB, W3, dinv, hsC, n);
    agg6_lsm_kernel<<<aggGrid, 256, 0, stream>>>(hsC, dinv, srcS, rowbeg, rowend, b3, out, n);
}

// Round 8
// 374.275 us; speedup vs baseline: 8.7837x; 1.0804x over previous
//
#include <hip/hip_runtime.h>
#include <hip/hip_fp16.h>
#include <math.h>

// ---------------------------------------------------------------------------
// GCN 3-layer forward, round 8.
// out[i] = dinv[i] * ( sum_{e:dst=i} Hs[src] + Hs[i] ) + b,  Hs = (X@W)*dinv.
// Round-8 delta: bin buckets coarsened 64 -> 256 nodes (391 buckets), chunk
// 8192 edges (512 thr x EPT 16) -> per-bucket runs ~21 edges (84B) instead of
// 2.6 (10B): write amp ~6.6x -> ~1.7x. Counting sort handles 256-node
// buckets (cnt[256], parallel scan, 512 threads). Everything else unchanged.
// ---------------------------------------------------------------------------

#define WS_ALIGN(x) (((x) + 255) & ~(size_t)255)
#define BKN 256                 // nodes per bin/sort bucket
#define CAP 8960                // slab capacity per bucket (mean 8184; +8.6 sigma)
#define EPT 16                  // edges per thread in bin kernel
#define BIN_THR 512
#define BIN_CHUNK (BIN_THR * EPT)  // 8192 edges per WG

typedef _Float16 half8 __attribute__((ext_vector_type(8)));
typedef float floatx4 __attribute__((ext_vector_type(4)));

// ---------------- binning: LDS-histogram chunked scatter ----------------
__global__ __launch_bounds__(BIN_THR) void bin_kernel(
    const int* __restrict__ src, const int* __restrict__ dst,
    int* __restrict__ cur, int* __restrict__ slab, int E, int NB) {
    __shared__ int counts[400];  // NB = 391
    const int tid = threadIdx.x;
    const int base = blockIdx.x * BIN_CHUNK + tid * EPT;  // contiguous per thread
    for (int i = tid; i < NB; i += BIN_THR) counts[i] = 0;
    __syncthreads();
    int b[EPT], w[EPT], lpos[EPT];
    #pragma unroll
    for (int k = 0; k < EPT; ++k) {
        int e = base + k;
        if (e < E) {
            int s = src[e], d = dst[e];   // vectorized int4 loads
            b[k] = d >> 8;
            w[k] = (s << 8) | (d & 255);
        } else b[k] = -1;
    }
    #pragma unroll
    for (int k = 0; k < EPT; ++k)
        if (b[k] >= 0) lpos[k] = atomicAdd(&counts[b[k]], 1);
    __syncthreads();
    for (int i = tid; i < NB; i += BIN_THR) {
        int c = counts[i];
        counts[i] = c ? atomicAdd(&cur[i], c) : 0;  // reserve contiguous run
    }
    __syncthreads();
    #pragma unroll
    for (int k = 0; k < EPT; ++k) {
        if (b[k] >= 0) {
            int pos = counts[b[k]] + lpos[k];
            if (pos < CAP) slab[(size_t)b[k] * CAP + pos] = w[k];
        }
    }
}

// ---------------- per-bucket counting sort -> per-node CSR + dinv ----------------
__global__ __launch_bounds__(512) void bucket_sort_kernel(
    const int* __restrict__ slab, const int* __restrict__ cur,
    int* __restrict__ srcS, int* __restrict__ rowbeg, int* __restrict__ rowend,
    float* __restrict__ dinv, int n) {
    __shared__ int cnt[BKN], s[BKN], cursor[BKN];
    const int b = blockIdx.x, tid = threadIdx.x;
    const int m = min(cur[b], CAP);
    const int* sp = slab + (size_t)b * CAP;
    if (tid < BKN) cnt[tid] = 0;
    __syncthreads();
    for (int j = tid; j < m; j += 512) atomicAdd(&cnt[sp[j] & 255], 1);
    __syncthreads();
    if (tid < BKN) s[tid] = cnt[tid];
    __syncthreads();
    // Hillis-Steele inclusive scan over 256 entries
    for (int off = 1; off < BKN; off <<= 1) {
        int v = 0;
        if (tid < BKN && tid >= off) v = s[tid - off];
        __syncthreads();
        if (tid < BKN) s[tid] += v;
        __syncthreads();
    }
    if (tid < BKN) {
        int ofs = s[tid] - cnt[tid];  // exclusive
        cursor[tid] = ofs;
        int node = b * BKN + tid;
        if (node < n) {
            rowbeg[node] = b * CAP + ofs;
            rowend[node] = b * CAP + ofs + cnt[tid];
            dinv[node] = rsqrtf((float)(cnt[tid] + 1));  // +1 self loop
        }
    }
    __syncthreads();
    for (int j = tid; j < m; j += 512) {
        int w = sp[j];
        int p = atomicAdd(&cursor[w & 255], 1);
        srcS[(size_t)b * CAP + p] = w >> 8;  // writes land in a 35KB window
    }
}

// ---------------- MFMA linear (fp32 input): Y16 = fp16((Xf@W)*dinv) ----------------
// mfma_f32_16x16x32_f16: A[m=lane&15][k=(lane>>4)*8+j], C/D col=lane&15, row=quad*4+r.
template <int K>
__global__ __launch_bounds__(256) void linear_mfma_f32_kernel(
    const float* __restrict__ Xf, const float* __restrict__ W,
    const float* __restrict__ dinv, _Float16* __restrict__ Y, int n) {
    constexpr int KC = K / 32;
    __shared__ _Float16 Bf[KC * 4 * 64 * 8];  // B-fragment order; K=128 -> 16KB
    const int tid = threadIdx.x;
    for (int i = tid; i < KC * 4 * 64 * 8; i += 256) {
        int j = i & 7, lane = (i >> 3) & 63, tile = (i >> 9) & 3, kc = i >> 11;
        int k = kc * 32 + ((lane >> 4) << 3) + j;
        int col = tile * 16 + (lane & 15);
        Bf[i] = (_Float16)W[k * 64 + col];
    }
    __syncthreads();
    const int lane = tid & 63, wid = tid >> 6;
    const int base = blockIdx.x * 64 + wid * 16;
    if (base >= n) return;
    const int mrow = lane & 15, quad = lane >> 4;
    const int anode = min(base + mrow, n - 1);
    floatx4 acc[4] = {{0, 0, 0, 0}, {0, 0, 0, 0}, {0, 0, 0, 0}, {0, 0, 0, 0}};
    #pragma unroll
    for (int kc = 0; kc < KC; ++kc) {
        float4 xa = *(const float4*)&Xf[(size_t)anode * K + kc * 32 + quad * 8];
        float4 xb = *(const float4*)&Xf[(size_t)anode * K + kc * 32 + quad * 8 + 4];
        half8 a;
        a[0] = (_Float16)xa.x; a[1] = (_Float16)xa.y; a[2] = (_Float16)xa.z; a[3] = (_Float16)xa.w;
        a[4] = (_Float16)xb.x; a[5] = (_Float16)xb.y; a[6] = (_Float16)xb.z; a[7] = (_Float16)xb.w;
        #pragma unroll
        for (int t = 0; t < 4; ++t) {
            half8 b = *(const half8*)&Bf[((kc * 4 + t) * 64 + lane) * 8];
            acc[t] = __builtin_amdgcn_mfma_f32_16x16x32_f16(a, b, acc[t], 0, 0, 0);
        }
    }
    #pragma unroll
    for (int r = 0; r < 4; ++r) {
        int node = base + quad * 4 + r;
        if (node < n) {
            float di = dinv[node];
            #pragma unroll
            for (int t = 0; t < 4; ++t)
                Y[(size_t)node * 64 + t * 16 + mrow] = (_Float16)(acc[t][r] * di);
        }
    }
}

// ---------------- MFMA linear (fp16 input), K=64 ----------------
__global__ __launch_bounds__(256) void linear_mfma_f16_kernel(
    const _Float16* __restrict__ Xh, const float* __restrict__ W,
    const float* __restrict__ dinv, _Float16* __restrict__ Y, int n) {
    constexpr int K = 64, KC = 2;
    __shared__ _Float16 Bf[KC * 4 * 64 * 8];  // 8KB
    const int tid = threadIdx.x;
    for (int i = tid; i < KC * 4 * 64 * 8; i += 256) {
        int j = i & 7, lane = (i >> 3) & 63, tile = (i >> 9) & 3, kc = i >> 11;
        int k = kc * 32 + ((lane >> 4) << 3) + j;
        int col = tile * 16 + (lane & 15);
        Bf[i] = (_Float16)W[k * 64 + col];
    }
    __syncthreads();
    const int lane = tid & 63, wid = tid >> 6;
    const int base = blockIdx.x * 64 + wid * 16;
    if (base >= n) return;
    const int mrow = lane & 15, quad = lane >> 4;
    const int anode = min(base + mrow, n - 1);
    floatx4 acc[4] = {{0, 0, 0, 0}, {0, 0, 0, 0}, {0, 0, 0, 0}, {0, 0, 0, 0}};
    #pragma unroll
    for (int kc = 0; kc < KC; ++kc) {
        half8 a = *(const half8*)&Xh[(size_t)anode * K + kc * 32 + quad * 8];
        #pragma unroll
        for (int t = 0; t < 4; ++t) {
            half8 b = *(const half8*)&Bf[((kc * 4 + t) * 64 + lane) * 8];
            acc[t] = __builtin_amdgcn_mfma_f32_16x16x32_f16(a, b, acc[t], 0, 0, 0);
        }
    }
    #pragma unroll
    for (int r = 0; r < 4; ++r) {
        int node = base + quad * 4 + r;
        if (node < n) {
            float di = dinv[node];
            #pragma unroll
            for (int t = 0; t < 4; ++t)
                Y[(size_t)node * 64 + t * 16 + mrow] = (_Float16)(acc[t][r] * di);
        }
    }
}

// ---------------- linear3: Y16[n][8] = fp16(pad8((Xh@W3)*dinv)) ----------------
__global__ __launch_bounds__(256) void linear3_kernel(const __half* __restrict__ Xh,
                                                      const float* __restrict__ W,
                                                      const float* __restrict__ dinv,
                                                      __half* __restrict__ Y, int n) {
    __shared__ float Wl[64 * 6];
    __shared__ float Xs[32][65];
    const int tid = threadIdx.x;
    for (int i = tid; i < 64 * 6; i += 256) Wl[i] = W[i];
    const int sub = tid >> 3;
    const int feat = tid & 7;
    for (int base = blockIdx.x * 32; base < n; base += gridDim.x * 32) {
        __syncthreads();
        for (int i = tid; i < 32 * 64; i += 256) {
            int r = i >> 6, c = i & 63;
            int node = base + r;
            Xs[r][c] = (node < n) ? __half2float(Xh[(size_t)node * 64 + c]) : 0.f;
        }
        __syncthreads();
        int node = base + sub;
        if (node < n) {
            float r = 0.f;
            if (feat < 6) {
                float acc = 0.f;
                #pragma unroll
                for (int k = 0; k < 64; ++k) acc = fmaf(Xs[sub][k], Wl[k * 6 + feat], acc);
                r = acc * dinv[node];
            }
            Y[(size_t)node * 8 + feat] = __float2half_rn(r);
        }
    }
}

// ---------------- aggregate 64 feats: wave/node, 8 lanes/edge, half8 gathers ----------------
__global__ __launch_bounds__(256) void agg64_kernel(
    const _Float16* __restrict__ Hs, const float* __restrict__ dinv,
    const int* __restrict__ srcS, const int* __restrict__ rowbeg,
    const int* __restrict__ rowend, const float* __restrict__ bias,
    _Float16* __restrict__ Out, int n, int do_relu) {
    const int wave = (blockIdx.x * blockDim.x + threadIdx.x) >> 6;
    const int lane = threadIdx.x & 63;
    if (wave >= n) return;
    const int slot = lane >> 3;  // edge slot 0..7
    const int f8 = lane & 7;     // feat slice [f8*8, f8*8+8)
    const int beg = rowbeg[wave], end = rowend[wave];
    float acc[8] = {0.f, 0.f, 0.f, 0.f, 0.f, 0.f, 0.f, 0.f};
    int j = beg;
    for (; j + 16 <= end; j += 16) {      // 16 edges: 2 gathers in flight
        int sA = srcS[j + slot];
        int sB = srcS[j + 8 + slot];
        half8 vA = *(const half8*)&Hs[(size_t)sA * 64 + f8 * 8];
        half8 vB = *(const half8*)&Hs[(size_t)sB * 64 + f8 * 8];
        #pragma unroll
        for (int i = 0; i < 8; ++i) acc[i] += (float)vA[i] + (float)vB[i];
    }
    for (; j < end; j += 8) {             // tail, 8 edges (masked)
        int jj = j + slot;
        int s = srcS[min(jj, end - 1)];
        half8 v = *(const half8*)&Hs[(size_t)s * 64 + f8 * 8];
        float flag = (jj < end) ? 1.f : 0.f;
        #pragma unroll
        for (int i = 0; i < 8; ++i) acc[i] = fmaf((float)v[i], flag, acc[i]);
    }
    #pragma unroll
    for (int i = 0; i < 8; ++i) {         // fold the 8 edge slots
        acc[i] += __shfl_xor(acc[i], 8);
        acc[i] += __shfl_xor(acc[i], 16);
        acc[i] += __shfl_xor(acc[i], 32);
    }
    half8 self = *(const half8*)&Hs[(size_t)wave * 64 + f8 * 8];
    const float di = dinv[wave];
    float4 b0 = *(const float4*)&bias[f8 * 8];
    float4 b1 = *(const float4*)&bias[f8 * 8 + 4];
    float bb[8] = {b0.x, b0.y, b0.z, b0.w, b1.x, b1.y, b1.z, b1.w};
    half8 o;
    #pragma unroll
    for (int i = 0; i < 8; ++i) {
        float v = (acc[i] + (float)self[i]) * di + bb[i];
        if (do_relu) v = fmaxf(v, 0.f);
        o[i] = (_Float16)v;
    }
    if (slot == 0) *(half8*)&Out[(size_t)wave * 64 + f8 * 8] = o;
}

// ---------------- aggregate 6 feats + bias + log_softmax ----------------
__global__ __launch_bounds__(256) void agg6_lsm_kernel(
    const __half* __restrict__ Hs6, const float* __restrict__ dinv,
    const int* __restrict__ srcS, const int* __restrict__ rowbeg,
    const int* __restrict__ rowend, const float* __restrict__ bias,
    float* __restrict__ out, int n) {
    const int wave = (blockIdx.x * blockDim.x + threadIdx.x) >> 6;
    const int lane = threadIdx.x & 63;
    if (wave >= n) return;
    const int slot = lane >> 3, f = lane & 7;
    const int beg = rowbeg[wave], end = rowend[wave];
    float part = 0.f;
    for (int j0 = beg; j0 < end; j0 += 8) {
        int j = j0 + slot;
        if (j < end) part += __half2float(Hs6[(size_t)srcS[j] * 8 + f]);
    }
    part += __shfl_xor(part, 8);
    part += __shfl_xor(part, 16);
    part += __shfl_xor(part, 32);
    float bi = (f < 6) ? bias[f] : 0.f;
    float a = (part + __half2float(Hs6[(size_t)wave * 8 + f])) * dinv[wave] + bi;
    float am = (f < 6) ? a : -1e30f;
    float m = am;
    m = fmaxf(m, __shfl_xor(m, 1));
    m = fmaxf(m, __shfl_xor(m, 2));
    m = fmaxf(m, __shfl_xor(m, 4));
    float ex = (f < 6) ? expf(a - m) : 0.f;
    float sum = ex;
    sum += __shfl_xor(sum, 1);
    sum += __shfl_xor(sum, 2);
    sum += __shfl_xor(sum, 4);
    float lse = m + logf(sum);
    if (slot == 0 && f < 6) out[(size_t)wave * 6 + f] = a - lse;
}

// ---------------------------------------------------------------------------
extern "C" void kernel_launch(void* const* d_in, const int* in_sizes, int n_in,
                              void* d_out, int out_size, void* d_ws, size_t ws_size,
                              hipStream_t stream) {
    const float* x  = (const float*)d_in[0];
    const int*   ei = (const int*)d_in[1];
    const float* W1 = (const float*)d_in[2];
    const float* b1 = (const float*)d_in[3];
    const float* W2 = (const float*)d_in[4];
    const float* b2 = (const float*)d_in[5];
    const float* W3 = (const float*)d_in[6];
    const float* b3 = (const float*)d_in[7];
    float* out = (float*)d_out;

    const int n = in_sizes[0] / 128;  // 100000
    const int E = in_sizes[1] / 2;    // 3200000
    const int* src = ei;
    const int* dst = ei + E;
    const int NB = (n + BKN - 1) / BKN;  // 391

    // ---- workspace carve ----
    char* ws = (char*)d_ws;
    auto carve = [&](size_t bytes) { char* p = ws; ws += WS_ALIGN(bytes); return p; };
    int*      cur    = (int*)     carve((size_t)NB * 4);
    float*    dinv   = (float*)   carve((size_t)n * 4);
    int*      slab   = (int*)     carve((size_t)NB * CAP * 4);   // 14.0 MB
    int*      srcS   = (int*)     carve((size_t)NB * CAP * 4);   // 14.0 MB
    int*      rowbeg = (int*)     carve((size_t)n * 4);
    int*      rowend = (int*)     carve((size_t)n * 4);
    _Float16* hsA    = (_Float16*)carve((size_t)n * 64 * 2 + 4096);   // 12.8 MB
    _Float16* hsB    = (_Float16*)carve((size_t)n * 64 * 2 + 4096);   // 12.8 MB
    __half*   hsC    = (__half*)  carve((size_t)n * 8 * 2);           // 1.6 MB
    (void)ws_size; (void)n_in; (void)out_size;

    // ---- build CSR ----
    hipMemsetAsync(cur, 0, (size_t)NB * 4, stream);
    bin_kernel<<<(E + BIN_CHUNK - 1) / BIN_CHUNK, BIN_THR, 0, stream>>>(src, dst, cur, slab, E, NB);
    bucket_sort_kernel<<<NB, 512, 0, stream>>>(slab, cur, srcS, rowbeg, rowend, dinv, n);

    const int aggGrid = (n + 3) / 4;       // wave per node, 4 waves/WG
    const int linGrid = (n + 63) / 64;     // 64 nodes per WG

    // ---- layer 1 ----
    linear_mfma_f32_kernel<128><<<linGrid, 256, 0, stream>>>(x, W1, dinv, hsA, n);
    agg64_kernel<<<aggGrid, 256, 0, stream>>>(hsA, dinv, srcS, rowbeg, rowend, b1, hsB, n, 1);

    // ---- layer 2 ----
    linear_mfma_f16_kernel<<<linGrid, 256, 0, stream>>>(hsB, W2, dinv, hsA, n);
    agg64_kernel<<<aggGrid, 256, 0, stream>>>(hsA, dinv, srcS, rowbeg, rowend, b2, hsB, n, 1);

    // ---- layer 3 ----
    linear3_kernel<<<2048, 256, 0, stream>>>((const __half*)hsB, W3, dinv, hsC, n);
    agg6_lsm_kernel<<<aggGrid, 256, 0, stream>>>(hsC, dinv, srcS, rowbeg, rowend, b3, out, n);
}